// Round 1
// baseline (1718.197 us; speedup 1.0000x reference)
//
#include <hip/hip_runtime.h>
#include <math.h>

#define DI    128
#define DS16  16
#define LL    10240            // T*H*W = 160*64
#define TT    160
#define NCH   160              // scan chunks
#define CLEN  64               // chunk length (NCH*CLEN == LL)
#define THETA 0.5f
#define EPSF  1e-5f

// ---------------- workspace layout (floats) ----------------
#define OFF_WEFF  0L                      // 27*64*64            = 110592
#define OFF_XF    (OFF_WEFF + 110592L)    // 2*L*64              = 1310720
#define OFF_XN    (OFF_XF   + 1310720L)
#define OFF_XIN   (OFF_XN   + 1310720L)   // 2dir*2b*L*128       = 5242880  (aliased as YG after conv1d)
#define OFF_Z     (OFF_XIN  + 5242880L)
#define OFF_XC    (OFF_Z    + 5242880L)
#define OFF_DT    (OFF_XC   + 5242880L)
#define OFF_BM    (OFF_DT   + 5242880L)   // 2*2*L*16            = 655360
#define OFF_CM    (OFF_BM   + 655360L)
#define OFF_CSP   (OFF_CM   + 655360L)    // 2*2*160*2048        = 1310720
#define OFF_CSS   (OFF_CSP  + 1310720L)
#define OFF_XO    (OFF_CSS  + 1310720L)
#define OFF_POOL  (OFF_XO   + 1310720L)   // 256 (avg 128 | max 128)
#define OFF_ATT   (OFF_POOL + 256L)       // 128

__device__ inline float waveAllSum(float v) {
#pragma unroll
    for (int off = 32; off > 0; off >>= 1) v += __shfl_xor(v, off, 64);
    return v;
}

// K0: fold temporal-difference into conv weights; relayout to [k27][c][o]
__global__ void k_fold(const float* __restrict__ w, float* __restrict__ weff) {
    int idx = blockIdx.x * blockDim.x + threadIdx.x;
    if (idx >= 64 * 64) return;
    int o = idx >> 6, c = idx & 63;
    const float* wb = w + (o * 64 + c) * 27;
    float kd = 0.f;
#pragma unroll
    for (int i = 0; i < 9; i++) kd += wb[i] + wb[18 + i];
#pragma unroll
    for (int k = 0; k < 27; k++) {
        float v = wb[k];
        if (k == 13) v -= THETA * kd;   // center tap (kt=1,kh=1,kw=1)
        weff[k * 4096 + c * 64 + o] = v;
    }
}

// K1: conv3d (+folded temp-diff) + BN + ReLU -> xf  (layout [b][l][c])
__global__ __launch_bounds__(256) void k_conv3d(
        const float* __restrict__ x, const float* __restrict__ weff,
        const float* __restrict__ bn_g, const float* __restrict__ bn_b,
        const float* __restrict__ bn_m, const float* __restrict__ bn_v,
        float* __restrict__ xf) {
    __shared__ float xt[64 * 3 * 64];   // [c][kt][hw]
    __shared__ float wl[32 * 64];       // [cc][o]
    int bt = blockIdx.x;
    int b = bt / TT, t = bt % TT;
    int tid = threadIdx.x;
    for (int kt = 0; kt < 3; kt++) {
        int ts = t + kt - 1;
        for (int i = tid; i < 4096; i += 256) {
            int c = i >> 6, hw = i & 63;
            float v = 0.f;
            if (ts >= 0 && ts < TT) v = x[(((long)b * 64 + c) * TT + ts) * 64 + hw];
            xt[(c * 3 + kt) * 64 + hw] = v;
        }
    }
    __syncthreads();
    int o = tid & 63, q = tid >> 6;     // wave-uniform q; hw = q*16+i
    float acc[16];
#pragma unroll
    for (int i = 0; i < 16; i++) acc[i] = 0.f;
    for (int st = 0; st < 27; st++) {
        int kt = st / 9, kh = (st / 3) % 3, kw = st % 3;
        int xoff[16];
#pragma unroll
        for (int i = 0; i < 16; i++) {
            int hw = q * 16 + i;
            int h = hw >> 3, w = hw & 7;
            int hh = h + kh - 1, ww = w + kw - 1;
            xoff[i] = (hh >= 0 && hh < 8 && ww >= 0 && ww < 8) ? (kt * 64 + hh * 8 + ww) : -1;
        }
        for (int ch = 0; ch < 2; ch++) {
            __syncthreads();
            for (int i = tid; i < 2048; i += 256) {
                int cc = i >> 6, oo = i & 63;
                wl[cc * 64 + oo] = weff[st * 4096 + (ch * 32 + cc) * 64 + oo];
            }
            __syncthreads();
            for (int cc = 0; cc < 32; cc++) {
                int c = ch * 32 + cc;
                float wv = wl[cc * 64 + o];
                const float* xb = &xt[c * 3 * 64];
#pragma unroll
                for (int i = 0; i < 16; i++)
                    if (xoff[i] >= 0) acc[i] += xb[xoff[i]] * wv;
            }
        }
    }
    float sc = bn_g[o] * rsqrtf(bn_v[o] + EPSF);
    float sh = bn_b[o] - bn_m[o] * sc;
#pragma unroll
    for (int i = 0; i < 16; i++) {
        int hw = q * 16 + i;
        float v = fmaxf(acc[i] * sc + sh, 0.f);
        xf[((long)b * LL + t * 64 + hw) * 64 + o] = v;
    }
}

// K2: LayerNorm1 -> xn
__global__ __launch_bounds__(256) void k_ln1(const float* __restrict__ xf,
        const float* __restrict__ g, const float* __restrict__ bta,
        float* __restrict__ xn) {
    int r = threadIdx.x >> 6, lane = threadIdx.x & 63;
    long row = (long)blockIdx.x * 4 + r;
    float v = xf[row * 64 + lane];
    float m = waveAllSum(v) * (1.f / 64.f);
    float d = v - m;
    float var = waveAllSum(d * d) * (1.f / 64.f);
    xn[row * 64 + lane] = d * rsqrtf(var + EPSF) * g[lane] + bta[lane];
}

// K3: in-proj GEMM (both dirs): xin, z   [dir][b][l][d]
__global__ __launch_bounds__(256) void k_xz(const float* __restrict__ xn,
        const float* __restrict__ inw_f, const float* __restrict__ inw_b,
        float* __restrict__ xin, float* __restrict__ z) {
    __shared__ float wl[32 * 257];   // [cc][d] padded
    __shared__ float xr[8 * 64];
    int dir = blockIdx.y;
    const float* inw = dir ? inw_b : inw_f;
    float* xinD = xin + (long)dir * 2 * LL * DI;
    float* zD   = z   + (long)dir * 2 * LL * DI;
    int tid = threadIdx.x;
    long row0 = (long)blockIdx.x * 8;
    for (int i = tid; i < 8 * 64; i += 256) {
        int r = i >> 6, c = i & 63;
        long row = row0 + r;
        int b = (int)(row / LL); int l = (int)(row % LL);
        int ls = dir ? (LL - 1 - l) : l;
        xr[i] = xn[((long)b * LL + ls) * 64 + c];
    }
    float acc[8];
#pragma unroll
    for (int r = 0; r < 8; r++) acc[r] = 0.f;
    for (int ch = 0; ch < 2; ch++) {
        __syncthreads();
        for (int i = tid; i < 32 * 256; i += 256) {
            int d = i >> 5, cc = i & 31;
            wl[cc * 257 + d] = inw[d * 64 + ch * 32 + cc];
        }
        __syncthreads();
#pragma unroll 4
        for (int cc = 0; cc < 32; cc++) {
            float wv = wl[cc * 257 + tid];
            int c = ch * 32 + cc;
#pragma unroll
            for (int r = 0; r < 8; r++) acc[r] += xr[r * 64 + c] * wv;
        }
    }
    for (int r = 0; r < 8; r++) {
        long row = row0 + r;
        if (tid < 128) xinD[row * 128 + tid] = acc[r];
        else           zD[row * 128 + (tid - 128)] = acc[r];
    }
}

// K4: causal depthwise conv1d + silu -> xc
__global__ void k_conv1d(const float* __restrict__ xin,
        const float* __restrict__ cw_f, const float* __restrict__ cb_f,
        const float* __restrict__ cw_b, const float* __restrict__ cb_b,
        float* __restrict__ xc) {
    long idx = (long)blockIdx.x * blockDim.x + threadIdx.x;
    long total = 2L * 2 * LL * DI;
    if (idx >= total) return;
    int d = idx & 127;
    long rem = idx >> 7;
    int l = (int)(rem % LL);
    int bd = (int)(rem / LL);          // dir*2+b
    int dir = bd >> 1;
    const float* cw = dir ? cw_b : cw_f;
    const float* cb = dir ? cb_b : cb_f;
    const float* xbase = xin + (long)bd * LL * DI + d;
    float a = cb[d];
#pragma unroll
    for (int k = 0; k < 4; k++) {
        int ls = l + k - 3;
        if (ls >= 0) a += xbase[(long)ls * DI] * cw[d * 4 + k];
    }
    xc[idx] = a / (1.f + expf(-a));
}

// K5: x-proj + dt-proj + softplus -> dt, Bm, Cm
__global__ __launch_bounds__(256) void k_xproj(const float* __restrict__ xc,
        const float* __restrict__ xpw_f, const float* __restrict__ xpw_b,
        const float* __restrict__ dtw_f, const float* __restrict__ dtb_f,
        const float* __restrict__ dtw_b, const float* __restrict__ dtb_b,
        float* __restrict__ dt, float* __restrict__ Bm, float* __restrict__ Cm) {
    __shared__ float xcr[16 * 128];
    __shared__ float xpT[128 * 36];
    __shared__ float dbl[16 * 36];
    __shared__ float dtw[512];
    int dir = blockIdx.y;
    const float* xpw  = dir ? xpw_b : xpw_f;
    const float* dtwp = dir ? dtw_b : dtw_f;
    const float* dtbp = dir ? dtb_b : dtb_f;
    const float* xcD = xc + (long)dir * 2 * LL * DI;
    float* dtD = dt + (long)dir * 2 * LL * DI;
    float* BmD = Bm + (long)dir * 2 * LL * DS16;
    float* CmD = Cm + (long)dir * 2 * LL * DS16;
    int tid = threadIdx.x;
    long row0 = (long)blockIdx.x * 16;
    for (int i = tid; i < 16 * 128; i += 256) xcr[i] = xcD[row0 * 128 + i];
    for (int i = tid; i < 36 * 128; i += 256) {
        int e = i / 128, d = i & 127;
        xpT[d * 36 + e] = xpw[i];
    }
    for (int i = tid; i < 512; i += 256) dtw[i] = dtwp[i];
    __syncthreads();
    for (int i = tid; i < 576; i += 256) {
        int r = i / 36, e = i % 36;
        float a = 0.f;
        for (int d = 0; d < 128; d++) a += xcr[r * 128 + d] * xpT[d * 36 + e];
        dbl[r * 36 + e] = a;
    }
    __syncthreads();
    for (int i = tid; i < 2048; i += 256) {
        int r = i >> 7, d = i & 127;
        float a = dtbp[d];
#pragma unroll
        for (int k = 0; k < 4; k++) a += dbl[r * 36 + k] * dtw[d * 4 + k];
        float sp = fmaxf(a, 0.f) + log1pf(expf(-fabsf(a)));
        dtD[(row0 + r) * 128 + d] = sp;
    }
    for (int i = tid; i < 256; i += 256) {
        int r = i >> 4, s = i & 15;
        BmD[(row0 + r) * 16 + s] = dbl[r * 36 + 4 + s];
        CmD[(row0 + r) * 16 + s] = dbl[r * 36 + 20 + s];
    }
}

// K6: scan phase A — per-chunk (P = prod dA, S = local scan w/ h0=0)
__global__ __launch_bounds__(128) void k_scanA(const float* __restrict__ dt,
        const float* __restrict__ xc, const float* __restrict__ Bm,
        const float* __restrict__ Alog_f, const float* __restrict__ Alog_b,
        float* __restrict__ csP, float* __restrict__ csS) {
    int d = threadIdx.x;
    int chunk = blockIdx.x;
    int bd = blockIdx.y;                 // dir*2+b
    const float* Alog = (bd >> 1) ? Alog_b : Alog_f;
    float ac[16], h[16], P[16];
#pragma unroll
    for (int s = 0; s < 16; s++) { ac[s] = -expf(Alog[d * 16 + s]); h[s] = 0.f; P[s] = 1.f; }
    long base = (long)bd * LL;
    int l0 = chunk * CLEN;
    const float* dtp = dt + (base + l0) * 128 + d;
    const float* xcp = xc + (base + l0) * 128 + d;
    const float* bmp = Bm + (base + l0) * 16;
    for (int l = 0; l < CLEN; l++) {
        float dtv = dtp[(long)l * 128];
        float dtx = dtv * xcp[(long)l * 128];
        const float* bl = bmp + l * 16;
#pragma unroll
        for (int s = 0; s < 16; s++) {
            float a = expf(dtv * ac[s]);
            h[s] = a * h[s] + dtx * bl[s];
            P[s] *= a;
        }
    }
    long cso = ((long)bd * NCH + chunk) * 2048 + d * 16;
#pragma unroll
    for (int s = 0; s < 16; s++) { csP[cso + s] = P[s]; csS[cso + s] = h[s]; }
}

// K7: sequential combine over chunks; csS[c] becomes h_in for chunk c
__global__ void k_combine(const float* __restrict__ csP, float* __restrict__ csS) {
    int idx = blockIdx.x * blockDim.x + threadIdx.x;  // 8192
    int bd = idx >> 11;
    int ds = idx & 2047;
    float hin = 0.f;
#pragma unroll 8
    for (int c = 0; c < NCH; c++) {
        long o = ((long)bd * NCH + c) * 2048 + ds;
        float P = csP[o], S = csS[o];
        csS[o] = hin;
        hin = P * hin + S;
    }
}

// K8: scan phase C — replay with h_in, emit y = (scan + D*xc)*silu(z)
__global__ __launch_bounds__(128) void k_scanC(const float* __restrict__ dt,
        const float* __restrict__ xc, const float* __restrict__ Bm,
        const float* __restrict__ Cm, const float* __restrict__ z,
        const float* __restrict__ csS,
        const float* __restrict__ Alog_f, const float* __restrict__ Alog_b,
        const float* __restrict__ D_f, const float* __restrict__ D_b,
        float* __restrict__ yg) {
    int d = threadIdx.x;
    int chunk = blockIdx.x;
    int bd = blockIdx.y;
    int dir = bd >> 1;
    const float* Alog = dir ? Alog_b : Alog_f;
    float Dv = dir ? D_b[d] : D_f[d];
    float ac[16], h[16];
    long cso = ((long)bd * NCH + chunk) * 2048 + d * 16;
#pragma unroll
    for (int s = 0; s < 16; s++) { ac[s] = -expf(Alog[d * 16 + s]); h[s] = csS[cso + s]; }
    long base = (long)bd * LL;
    int l0 = chunk * CLEN;
    const float* dtp = dt + (base + l0) * 128 + d;
    const float* xcp = xc + (base + l0) * 128 + d;
    const float* zp  = z  + (base + l0) * 128 + d;
    const float* bmp = Bm + (base + l0) * 16;
    const float* cmp = Cm + (base + l0) * 16;
    float* yp = yg + (base + l0) * 128 + d;
    for (int l = 0; l < CLEN; l++) {
        float dtv = dtp[(long)l * 128];
        float xcv = xcp[(long)l * 128];
        float dtx = dtv * xcv;
        const float* bl = bmp + l * 16;
        const float* cl = cmp + l * 16;
        float y = 0.f;
#pragma unroll
        for (int s = 0; s < 16; s++) {
            float a = expf(dtv * ac[s]);
            h[s] = a * h[s] + dtx * bl[s];
            y += h[s] * cl[s];
        }
        y += Dv * xcv;
        float zv = zp[(long)l * 128];
        y *= zv / (1.f + expf(-zv));
        yp[(long)l * 128] = y;
    }
}

// K9: out-proj (both dirs, backward un-flipped) + residual + LN2 -> xo
__global__ __launch_bounds__(256) void k_outln(const float* __restrict__ yg,
        const float* __restrict__ xf,
        const float* __restrict__ ow_f, const float* __restrict__ ow_b,
        const float* __restrict__ g2, const float* __restrict__ b2,
        float* __restrict__ xo) {
    __shared__ float yr[2][4][128];
    __shared__ float owT[64][65];
    int tid = threadIdx.x;
    int r = tid >> 6, lane = tid & 63;
    long row0 = (long)blockIdx.x * 4;
    for (int i = tid; i < 4 * 128; i += 256) {
        int rr = i >> 7, dd = i & 127;
        long row = row0 + rr;
        int b = (int)(row / LL), l = (int)(row % LL);
        yr[0][rr][dd] = yg[((long)(0 * 2 + b) * LL + l) * 128 + dd];
        yr[1][rr][dd] = yg[((long)(1 * 2 + b) * LL + (LL - 1 - l)) * 128 + dd];
    }
    long row = row0 + r;
    float acc = xf[row * 64 + lane];
    for (int ph = 0; ph < 4; ph++) {
        int dir = ph >> 1, half = ph & 1;
        const float* ow = dir ? ow_b : ow_f;
        __syncthreads();
        for (int i = tid; i < 4096; i += 256) {
            int o2 = i >> 6, dd2 = i & 63;
            owT[dd2][o2] = ow[o2 * 128 + half * 64 + dd2];
        }
        __syncthreads();
        const float* yrow = &yr[dir][r][half * 64];
#pragma unroll 8
        for (int dd2 = 0; dd2 < 64; dd2++) acc += yrow[dd2] * owT[dd2][lane];
    }
    float m = waveAllSum(acc) * (1.f / 64.f);
    float dv = acc - m;
    float var = waveAllSum(dv * dv) * (1.f / 64.f);
    xo[row * 64 + lane] = dv * rsqrtf(var + EPSF) * g2[lane] + b2[lane];
}

// K10: avg+max pool over l per (b,c)
__global__ __launch_bounds__(1024) void k_pool(const float* __restrict__ xo,
        float* __restrict__ pool) {
    __shared__ float ssum[16][64], smax[16][64];
    int b = blockIdx.x;
    int tid = threadIdx.x;
    int g = tid >> 6, c = tid & 63;
    float s = 0.f, m = -INFINITY;
    for (int l = g; l < LL; l += 16) {
        float v = xo[((long)b * LL + l) * 64 + c];
        s += v; m = fmaxf(m, v);
    }
    ssum[g][c] = s; smax[g][c] = m;
    __syncthreads();
    if (g == 0) {
        float S = 0.f, M = -INFINITY;
#pragma unroll
        for (int k = 0; k < 16; k++) { S += ssum[k][c]; M = fmaxf(M, smax[k][c]); }
        pool[b * 64 + c] = S * (1.f / LL);
        pool[128 + b * 64 + c] = M;
    }
}

// K11: channel attention
__global__ __launch_bounds__(128) void k_att(const float* __restrict__ pool,
        const float* __restrict__ w1, const float* __restrict__ w2,
        float* __restrict__ att) {
    __shared__ float hs[2][2][32];
    int tid = threadIdx.x;
    {
        int which = tid >> 6;
        int rb = tid & 63;
        int bb = rb >> 5, r = rb & 31;
        const float* v = pool + which * 128 + bb * 64;
        float a = 0.f;
        for (int c = 0; c < 64; c++) a += v[c] * w1[r * 64 + c];
        hs[which][bb][r] = fmaxf(a, 0.f);
    }
    __syncthreads();
    int bb = tid >> 6, c = tid & 63;
    float s = 0.f;
#pragma unroll
    for (int r = 0; r < 32; r++) s += (hs[0][bb][r] + hs[1][bb][r]) * w2[c * 32 + r];
    att[bb * 64 + c] = 1.f / (1.f + expf(-s));
}

// K12: out[b,c,t,h,w] = xo[b,l,c] * att[b,c]
__global__ void k_final(const float* __restrict__ xo, const float* __restrict__ att,
        float* __restrict__ out) {
    long idx = (long)blockIdx.x * blockDim.x + threadIdx.x;
    if (idx >= 2L * 64 * LL) return;
    int l = (int)(idx % LL);
    int c = (int)((idx / LL) & 63);
    int b = (int)(idx / (64L * LL));
    out[idx] = xo[((long)b * LL + l) * 64 + c] * att[b * 64 + c];
}

extern "C" void kernel_launch(void* const* d_in, const int* in_sizes, int n_in,
                              void* d_out, int out_size, void* d_ws, size_t ws_size,
                              hipStream_t stream) {
    const float* x     = (const float*)d_in[0];
    const float* tdc_w = (const float*)d_in[1];
    const float* bn_g  = (const float*)d_in[2];
    const float* bn_b  = (const float*)d_in[3];
    const float* bn_m  = (const float*)d_in[4];
    const float* bn_v  = (const float*)d_in[5];
    const float* ln1_g = (const float*)d_in[6];
    const float* ln1_b = (const float*)d_in[7];
    const float* ln2_g = (const float*)d_in[8];
    const float* ln2_b = (const float*)d_in[9];
    const float* ca_w1 = (const float*)d_in[10];
    const float* ca_w2 = (const float*)d_in[11];
    const float* f_in_w    = (const float*)d_in[12];
    const float* f_conv_w  = (const float*)d_in[13];
    const float* f_conv_b  = (const float*)d_in[14];
    const float* f_xproj_w = (const float*)d_in[15];
    const float* f_dt_w    = (const float*)d_in[16];
    const float* f_dt_b    = (const float*)d_in[17];
    const float* f_A_log   = (const float*)d_in[18];
    const float* f_D       = (const float*)d_in[19];
    const float* f_out_w   = (const float*)d_in[20];
    const float* b_in_w    = (const float*)d_in[21];
    const float* b_conv_w  = (const float*)d_in[22];
    const float* b_conv_b  = (const float*)d_in[23];
    const float* b_xproj_w = (const float*)d_in[24];
    const float* b_dt_w    = (const float*)d_in[25];
    const float* b_dt_b    = (const float*)d_in[26];
    const float* b_A_log   = (const float*)d_in[27];
    const float* b_D       = (const float*)d_in[28];
    const float* b_out_w   = (const float*)d_in[29];

    float* ws = (float*)d_ws;
    float* weff = ws + OFF_WEFF;
    float* xf   = ws + OFF_XF;
    float* xn   = ws + OFF_XN;
    float* xin  = ws + OFF_XIN;   // reused as yg after k_conv1d consumes it
    float* z    = ws + OFF_Z;
    float* xc   = ws + OFF_XC;
    float* dt   = ws + OFF_DT;
    float* Bm   = ws + OFF_BM;
    float* Cm   = ws + OFF_CM;
    float* csP  = ws + OFF_CSP;
    float* csS  = ws + OFF_CSS;
    float* xo   = ws + OFF_XO;
    float* pool = ws + OFF_POOL;
    float* att  = ws + OFF_ATT;
    float* yg   = xin;

    hipLaunchKernelGGL(k_fold, dim3(16), dim3(256), 0, stream, tdc_w, weff);
    hipLaunchKernelGGL(k_conv3d, dim3(2 * TT), dim3(256), 0, stream,
                       x, weff, bn_g, bn_b, bn_m, bn_v, xf);
    hipLaunchKernelGGL(k_ln1, dim3(2 * LL / 4), dim3(256), 0, stream,
                       xf, ln1_g, ln1_b, xn);
    hipLaunchKernelGGL(k_xz, dim3(2 * LL / 8, 2), dim3(256), 0, stream,
                       xn, f_in_w, b_in_w, xin, z);
    hipLaunchKernelGGL(k_conv1d, dim3((2 * 2 * LL * DI) / 256), dim3(256), 0, stream,
                       xin, f_conv_w, f_conv_b, b_conv_w, b_conv_b, xc);
    hipLaunchKernelGGL(k_xproj, dim3(2 * LL / 16, 2), dim3(256), 0, stream,
                       xc, f_xproj_w, b_xproj_w, f_dt_w, f_dt_b, b_dt_w, b_dt_b,
                       dt, Bm, Cm);
    hipLaunchKernelGGL(k_scanA, dim3(NCH, 4), dim3(128), 0, stream,
                       dt, xc, Bm, f_A_log, b_A_log, csP, csS);
    hipLaunchKernelGGL(k_combine, dim3(32), dim3(256), 0, stream, csP, csS);
    hipLaunchKernelGGL(k_scanC, dim3(NCH, 4), dim3(128), 0, stream,
                       dt, xc, Bm, Cm, z, csS, f_A_log, b_A_log, f_D, b_D, yg);
    hipLaunchKernelGGL(k_outln, dim3(2 * LL / 4), dim3(256), 0, stream,
                       yg, xf, f_out_w, b_out_w, ln2_g, ln2_b, xo);
    hipLaunchKernelGGL(k_pool, dim3(2), dim3(1024), 0, stream, xo, pool);
    hipLaunchKernelGGL(k_att, dim3(1), dim3(128), 0, stream, pool, ca_w1, ca_w2, att);
    hipLaunchKernelGGL(k_final, dim3((2 * 64 * LL) / 256), dim3(256), 0, stream,
                       xo, att, (float*)d_out);
}

// Round 2
// 683.967 us; speedup vs baseline: 2.5121x; 2.5121x over previous
//
#include <hip/hip_runtime.h>
#include <math.h>

#define DI    128
#define DS16  16
#define LL    10240            // T*H*W = 160*64
#define TT    160
#define NCH   160              // scan chunks
#define CLEN  64               // chunk length (NCH*CLEN == LL)
#define THETA 0.5f
#define EPSF  1e-5f
#define XPAD  72               // padded c stride (bf16 el) for conv LDS tiles

typedef __bf16 bf16x8 __attribute__((ext_vector_type(8)));
typedef float  f32x4  __attribute__((ext_vector_type(4)));

// ---------------- workspace layout (floats) ----------------
#define OFF_WEFF  0L                      // bf16 conv weights live here: 27*64*72*2B = 248832B <= 110592*4B
#define OFF_XF    (OFF_WEFF + 110592L)    // 2*L*64              = 1310720
#define OFF_XN    (OFF_XF   + 1310720L)
#define OFF_XIN   (OFF_XN   + 1310720L)   // 2dir*2b*L*128       = 5242880  (aliased as YG after conv1d)
#define OFF_Z     (OFF_XIN  + 5242880L)
#define OFF_XC    (OFF_Z    + 5242880L)
#define OFF_DT    (OFF_XC   + 5242880L)
#define OFF_BM    (OFF_DT   + 5242880L)   // 2*2*L*16            = 655360
#define OFF_CM    (OFF_BM   + 655360L)
#define OFF_CSP   (OFF_CM   + 655360L)    // 2*2*160*2048        = 1310720
#define OFF_CSS   (OFF_CSP  + 1310720L)
#define OFF_XO    (OFF_CSS  + 1310720L)
#define OFF_POOL  (OFF_XO   + 1310720L)   // 256 (avg 128 | max 128)
#define OFF_ATT   (OFF_POOL + 256L)       // 128

__device__ inline float waveAllSum(float v) {
#pragma unroll
    for (int off = 32; off > 0; off >>= 1) v += __shfl_xor(v, off, 64);
    return v;
}

// K0: fold temporal-difference into conv weights; emit bf16 [k27][o][XPAD]
__global__ void k_fold(const float* __restrict__ w, __bf16* __restrict__ wbf) {
    int idx = blockIdx.x * blockDim.x + threadIdx.x;   // 4096 threads
    if (idx < 64 * 64) {
        int o = idx >> 6, c = idx & 63;
        const float* wb = w + (o * 64 + c) * 27;
        float kd = 0.f;
#pragma unroll
        for (int i = 0; i < 9; i++) kd += wb[i] + wb[18 + i];
#pragma unroll
        for (int k = 0; k < 27; k++) {
            float v = wb[k];
            if (k == 13) v -= THETA * kd;   // center tap (kt=1,kh=1,kw=1)
            wbf[((long)k * 64 + o) * XPAD + c] = (__bf16)v;
        }
    }
    // zero the pad columns (c = 64..71)
    for (int i = idx; i < 27 * 64 * 8; i += 4096) {
        int k = i >> 9;           // / 512
        int rem = i & 511;
        int o = rem >> 3, j = rem & 7;
        wbf[((long)k * 64 + o) * XPAD + 64 + j] = (__bf16)0.f;
    }
}

// K1: conv3d (+folded temp-diff) + BN + ReLU via bf16 MFMA -> xf [b][l][c]
// Block: one (b, t, o-half=32 outs). 4 waves: wave = (nsel<<1)|mhalf.
// GEMM: C[64hw][32o] = sum_{kt,kh,kw} Xpad[(h+kh)*10+(w+kw)][c] * W[tap][o][c]
__global__ __launch_bounds__(256) void k_conv3d_mfma(
        const float* __restrict__ x, const __bf16* __restrict__ wbf,
        const float* __restrict__ bn_g, const float* __restrict__ bn_b,
        const float* __restrict__ bn_m, const float* __restrict__ bn_v,
        float* __restrict__ xf) {
    __shared__ __align__(16) __bf16 Xs[100 * XPAD];      // 14400 B
    __shared__ __align__(16) __bf16 Wsh[9 * 32 * XPAD];  // 41472 B
    int blk = blockIdx.x;
    int oh = blk & 1;
    int bt = blk >> 1;
    int b = bt / TT, t = bt % TT;
    int tid = threadIdx.x;
    int wave = tid >> 6, lane = tid & 63;
    int lane15 = lane & 15, q4 = lane >> 4;
    int m0 = (wave & 1) * 32;
    int nsel = wave >> 1;

    int hw0 = m0 + lane15;          // A-frag rows, mi=0
    int hw1 = m0 + 16 + lane15;     // mi=1
    int hA0 = hw0 >> 3, wA0 = hw0 & 7;
    int hA1 = hw1 >> 3, wA1 = hw1 & 7;

    f32x4 acc0 = {0.f, 0.f, 0.f, 0.f};
    f32x4 acc1 = {0.f, 0.f, 0.f, 0.f};

    for (int kt = 0; kt < 3; kt++) {
        __syncthreads();   // previous compute done before overwriting tiles
        // zero X tile (padded borders become the conv zero-padding)
        for (int i = tid; i < 100 * XPAD / 2; i += 256)
            ((unsigned int*)Xs)[i] = 0u;
        // stage this kt's 9 weight taps (o-half) as dwords
        {
            const unsigned int* src = (const unsigned int*)wbf;
            unsigned int* dst = (unsigned int*)Wsh;
            for (int i = tid; i < 9 * 32 * 36; i += 256) {
                int tap = i / (32 * 36);
                int r = i - tap * (32 * 36);
                dst[tap * (32 * 36) + r] = src[((kt * 9 + tap) * 64 + oh * 32) * 36 + r];
            }
        }
        __syncthreads();   // zeros + weights visible
        int ts = t + kt - 1;
        if (ts >= 0 && ts < TT) {
            int hw = tid & 63;
            int h = hw >> 3, w = hw & 7;
            int row = (h + 1) * 10 + (w + 1);
            const float* xb = x + (((long)b * 64) * TT + ts) * 64 + hw;
#pragma unroll
            for (int i = 0; i < 8; i++) {
                int c2 = i * 8 + (tid >> 6) * 2;
                float v0 = xb[(long)c2 * TT * 64];
                float v1 = xb[(long)(c2 + 1) * TT * 64];
                union { unsigned int u; __bf16 h2[2]; } pk;
                pk.h2[0] = (__bf16)v0; pk.h2[1] = (__bf16)v1;
                ((unsigned int*)Xs)[row * (XPAD / 2) + (c2 >> 1)] = pk.u;
            }
        }
        __syncthreads();   // X staged
        // K-loop: 9 taps x 2 c-halves
#pragma unroll
        for (int kh = 0; kh < 3; kh++) {
#pragma unroll
            for (int kw = 0; kw < 3; kw++) {
                int tap = kh * 3 + kw;
                int r0 = (hA0 + kh) * 10 + (wA0 + kw);
                int r1 = (hA1 + kh) * 10 + (wA1 + kw);
                const __bf16* xp0 = &Xs[r0 * XPAD + q4 * 8];
                const __bf16* xp1 = &Xs[r1 * XPAD + q4 * 8];
                const __bf16* wp  = &Wsh[(tap * 32 + nsel * 16 + lane15) * XPAD + q4 * 8];
#pragma unroll
                for (int ch = 0; ch < 2; ch++) {
                    bf16x8 a0 = *(const bf16x8*)(xp0 + ch * 32);
                    bf16x8 a1 = *(const bf16x8*)(xp1 + ch * 32);
                    bf16x8 bb = *(const bf16x8*)(wp + ch * 32);
                    acc0 = __builtin_amdgcn_mfma_f32_16x16x32_bf16(a0, bb, acc0, 0, 0, 0);
                    acc1 = __builtin_amdgcn_mfma_f32_16x16x32_bf16(a1, bb, acc1, 0, 0, 0);
                }
            }
        }
    }
    // epilogue: BN + ReLU, store [b][l][c]
    int o = oh * 32 + nsel * 16 + lane15;
    float sc = bn_g[o] * rsqrtf(bn_v[o] + EPSF);
    float sh = bn_b[o] - bn_m[o] * sc;
    long obase = (long)b * LL + t * 64;
#pragma unroll
    for (int r = 0; r < 4; r++) {
        int hwr0 = m0 + q4 * 4 + r;
        int hwr1 = m0 + 16 + q4 * 4 + r;
        xf[(obase + hwr0) * 64 + o] = fmaxf(acc0[r] * sc + sh, 0.f);
        xf[(obase + hwr1) * 64 + o] = fmaxf(acc1[r] * sc + sh, 0.f);
    }
}

// K2: LayerNorm1 -> xn
__global__ __launch_bounds__(256) void k_ln1(const float* __restrict__ xf,
        const float* __restrict__ g, const float* __restrict__ bta,
        float* __restrict__ xn) {
    int r = threadIdx.x >> 6, lane = threadIdx.x & 63;
    long row = (long)blockIdx.x * 4 + r;
    float v = xf[row * 64 + lane];
    float m = waveAllSum(v) * (1.f / 64.f);
    float d = v - m;
    float var = waveAllSum(d * d) * (1.f / 64.f);
    xn[row * 64 + lane] = d * rsqrtf(var + EPSF) * g[lane] + bta[lane];
}

// K3: in-proj GEMM (both dirs): xin, z   [dir][b][l][d]
__global__ __launch_bounds__(256) void k_xz(const float* __restrict__ xn,
        const float* __restrict__ inw_f, const float* __restrict__ inw_b,
        float* __restrict__ xin, float* __restrict__ z) {
    __shared__ float wl[32 * 257];   // [cc][d] padded
    __shared__ float xr[8 * 64];
    int dir = blockIdx.y;
    const float* inw = dir ? inw_b : inw_f;
    float* xinD = xin + (long)dir * 2 * LL * DI;
    float* zD   = z   + (long)dir * 2 * LL * DI;
    int tid = threadIdx.x;
    long row0 = (long)blockIdx.x * 8;
    for (int i = tid; i < 8 * 64; i += 256) {
        int r = i >> 6, c = i & 63;
        long row = row0 + r;
        int b = (int)(row / LL); int l = (int)(row % LL);
        int ls = dir ? (LL - 1 - l) : l;
        xr[i] = xn[((long)b * LL + ls) * 64 + c];
    }
    float acc[8];
#pragma unroll
    for (int r = 0; r < 8; r++) acc[r] = 0.f;
    for (int ch = 0; ch < 2; ch++) {
        __syncthreads();
        for (int i = tid; i < 32 * 256; i += 256) {
            int d = i >> 5, cc = i & 31;
            wl[cc * 257 + d] = inw[d * 64 + ch * 32 + cc];
        }
        __syncthreads();
#pragma unroll 4
        for (int cc = 0; cc < 32; cc++) {
            float wv = wl[cc * 257 + tid];
            int c = ch * 32 + cc;
#pragma unroll
            for (int r = 0; r < 8; r++) acc[r] += xr[r * 64 + c] * wv;
        }
    }
    for (int r = 0; r < 8; r++) {
        long row = row0 + r;
        if (tid < 128) xinD[row * 128 + tid] = acc[r];
        else           zD[row * 128 + (tid - 128)] = acc[r];
    }
}

// K4: causal depthwise conv1d + silu -> xc
__global__ void k_conv1d(const float* __restrict__ xin,
        const float* __restrict__ cw_f, const float* __restrict__ cb_f,
        const float* __restrict__ cw_b, const float* __restrict__ cb_b,
        float* __restrict__ xc) {
    long idx = (long)blockIdx.x * blockDim.x + threadIdx.x;
    long total = 2L * 2 * LL * DI;
    if (idx >= total) return;
    int d = idx & 127;
    long rem = idx >> 7;
    int l = (int)(rem % LL);
    int bd = (int)(rem / LL);          // dir*2+b
    int dir = bd >> 1;
    const float* cw = dir ? cw_b : cw_f;
    const float* cb = dir ? cb_b : cb_f;
    const float* xbase = xin + (long)bd * LL * DI + d;
    float a = cb[d];
#pragma unroll
    for (int k = 0; k < 4; k++) {
        int ls = l + k - 3;
        if (ls >= 0) a += xbase[(long)ls * DI] * cw[d * 4 + k];
    }
    xc[idx] = a / (1.f + expf(-a));
}

// K5: x-proj + dt-proj + softplus -> dt, Bm, Cm
__global__ __launch_bounds__(256) void k_xproj(const float* __restrict__ xc,
        const float* __restrict__ xpw_f, const float* __restrict__ xpw_b,
        const float* __restrict__ dtw_f, const float* __restrict__ dtb_f,
        const float* __restrict__ dtw_b, const float* __restrict__ dtb_b,
        float* __restrict__ dt, float* __restrict__ Bm, float* __restrict__ Cm) {
    __shared__ float xcr[16 * 128];
    __shared__ float xpT[128 * 36];
    __shared__ float dbl[16 * 36];
    __shared__ float dtw[512];
    int dir = blockIdx.y;
    const float* xpw  = dir ? xpw_b : xpw_f;
    const float* dtwp = dir ? dtw_b : dtw_f;
    const float* dtbp = dir ? dtb_b : dtb_f;
    const float* xcD = xc + (long)dir * 2 * LL * DI;
    float* dtD = dt + (long)dir * 2 * LL * DI;
    float* BmD = Bm + (long)dir * 2 * LL * DS16;
    float* CmD = Cm + (long)dir * 2 * LL * DS16;
    int tid = threadIdx.x;
    long row0 = (long)blockIdx.x * 16;
    for (int i = tid; i < 16 * 128; i += 256) xcr[i] = xcD[row0 * 128 + i];
    for (int i = tid; i < 36 * 128; i += 256) {
        int e = i / 128, d = i & 127;
        xpT[d * 36 + e] = xpw[i];
    }
    for (int i = tid; i < 512; i += 256) dtw[i] = dtwp[i];
    __syncthreads();
    for (int i = tid; i < 576; i += 256) {
        int r = i / 36, e = i % 36;
        float a = 0.f;
        for (int d = 0; d < 128; d++) a += xcr[r * 128 + d] * xpT[d * 36 + e];
        dbl[r * 36 + e] = a;
    }
    __syncthreads();
    for (int i = tid; i < 2048; i += 256) {
        int r = i >> 7, d = i & 127;
        float a = dtbp[d];
#pragma unroll
        for (int k = 0; k < 4; k++) a += dbl[r * 36 + k] * dtw[d * 4 + k];
        float sp = fmaxf(a, 0.f) + log1pf(expf(-fabsf(a)));
        dtD[(row0 + r) * 128 + d] = sp;
    }
    for (int i = tid; i < 256; i += 256) {
        int r = i >> 4, s = i & 15;
        BmD[(row0 + r) * 16 + s] = dbl[r * 36 + 4 + s];
        CmD[(row0 + r) * 16 + s] = dbl[r * 36 + 20 + s];
    }
}

// K6: scan phase A — per-chunk (P = prod dA, S = local scan w/ h0=0)
__global__ __launch_bounds__(128) void k_scanA(const float* __restrict__ dt,
        const float* __restrict__ xc, const float* __restrict__ Bm,
        const float* __restrict__ Alog_f, const float* __restrict__ Alog_b,
        float* __restrict__ csP, float* __restrict__ csS) {
    int d = threadIdx.x;
    int chunk = blockIdx.x;
    int bd = blockIdx.y;                 // dir*2+b
    const float* Alog = (bd >> 1) ? Alog_b : Alog_f;
    float ac[16], h[16], P[16];
#pragma unroll
    for (int s = 0; s < 16; s++) { ac[s] = -expf(Alog[d * 16 + s]); h[s] = 0.f; P[s] = 1.f; }
    long base = (long)bd * LL;
    int l0 = chunk * CLEN;
    const float* dtp = dt + (base + l0) * 128 + d;
    const float* xcp = xc + (base + l0) * 128 + d;
    const float* bmp = Bm + (base + l0) * 16;
    for (int l = 0; l < CLEN; l++) {
        float dtv = dtp[(long)l * 128];
        float dtx = dtv * xcp[(long)l * 128];
        const float* bl = bmp + l * 16;
#pragma unroll
        for (int s = 0; s < 16; s++) {
            float a = expf(dtv * ac[s]);
            h[s] = a * h[s] + dtx * bl[s];
            P[s] *= a;
        }
    }
    long cso = ((long)bd * NCH + chunk) * 2048 + d * 16;
#pragma unroll
    for (int s = 0; s < 16; s++) { csP[cso + s] = P[s]; csS[cso + s] = h[s]; }
}

// K7: sequential combine over chunks; csS[c] becomes h_in for chunk c
__global__ void k_combine(const float* __restrict__ csP, float* __restrict__ csS) {
    int idx = blockIdx.x * blockDim.x + threadIdx.x;  // 8192
    int bd = idx >> 11;
    int ds = idx & 2047;
    float hin = 0.f;
#pragma unroll 8
    for (int c = 0; c < NCH; c++) {
        long o = ((long)bd * NCH + c) * 2048 + ds;
        float P = csP[o], S = csS[o];
        csS[o] = hin;
        hin = P * hin + S;
    }
}

// K8: scan phase C — replay with h_in, emit y = (scan + D*xc)*silu(z)
__global__ __launch_bounds__(128) void k_scanC(const float* __restrict__ dt,
        const float* __restrict__ xc, const float* __restrict__ Bm,
        const float* __restrict__ Cm, const float* __restrict__ z,
        const float* __restrict__ csS,
        const float* __restrict__ Alog_f, const float* __restrict__ Alog_b,
        const float* __restrict__ D_f, const float* __restrict__ D_b,
        float* __restrict__ yg) {
    int d = threadIdx.x;
    int chunk = blockIdx.x;
    int bd = blockIdx.y;
    int dir = bd >> 1;
    const float* Alog = dir ? Alog_b : Alog_f;
    float Dv = dir ? D_b[d] : D_f[d];
    float ac[16], h[16];
    long cso = ((long)bd * NCH + chunk) * 2048 + d * 16;
#pragma unroll
    for (int s = 0; s < 16; s++) { ac[s] = -expf(Alog[d * 16 + s]); h[s] = csS[cso + s]; }
    long base = (long)bd * LL;
    int l0 = chunk * CLEN;
    const float* dtp = dt + (base + l0) * 128 + d;
    const float* xcp = xc + (base + l0) * 128 + d;
    const float* zp  = z  + (base + l0) * 128 + d;
    const float* bmp = Bm + (base + l0) * 16;
    const float* cmp = Cm + (base + l0) * 16;
    float* yp = yg + (base + l0) * 128 + d;
    for (int l = 0; l < CLEN; l++) {
        float dtv = dtp[(long)l * 128];
        float xcv = xcp[(long)l * 128];
        float dtx = dtv * xcv;
        const float* bl = bmp + l * 16;
        const float* cl = cmp + l * 16;
        float y = 0.f;
#pragma unroll
        for (int s = 0; s < 16; s++) {
            float a = expf(dtv * ac[s]);
            h[s] = a * h[s] + dtx * bl[s];
            y += h[s] * cl[s];
        }
        y += Dv * xcv;
        float zv = zp[(long)l * 128];
        y *= zv / (1.f + expf(-zv));
        yp[(long)l * 128] = y;
    }
}

// K9: out-proj (both dirs, backward un-flipped) + residual + LN2 -> xo
__global__ __launch_bounds__(256) void k_outln(const float* __restrict__ yg,
        const float* __restrict__ xf,
        const float* __restrict__ ow_f, const float* __restrict__ ow_b,
        const float* __restrict__ g2, const float* __restrict__ b2,
        float* __restrict__ xo) {
    __shared__ float yr[2][4][128];
    __shared__ float owT[64][65];
    int tid = threadIdx.x;
    int r = tid >> 6, lane = tid & 63;
    long row0 = (long)blockIdx.x * 4;
    for (int i = tid; i < 4 * 128; i += 256) {
        int rr = i >> 7, dd = i & 127;
        long row = row0 + rr;
        int b = (int)(row / LL), l = (int)(row % LL);
        yr[0][rr][dd] = yg[((long)(0 * 2 + b) * LL + l) * 128 + dd];
        yr[1][rr][dd] = yg[((long)(1 * 2 + b) * LL + (LL - 1 - l)) * 128 + dd];
    }
    long row = row0 + r;
    float acc = xf[row * 64 + lane];
    for (int ph = 0; ph < 4; ph++) {
        int dir = ph >> 1, half = ph & 1;
        const float* ow = dir ? ow_b : ow_f;
        __syncthreads();
        for (int i = tid; i < 4096; i += 256) {
            int o2 = i >> 6, dd2 = i & 63;
            owT[dd2][o2] = ow[o2 * 128 + half * 64 + dd2];
        }
        __syncthreads();
        const float* yrow = &yr[dir][r][half * 64];
#pragma unroll 8
        for (int dd2 = 0; dd2 < 64; dd2++) acc += yrow[dd2] * owT[dd2][lane];
    }
    float m = waveAllSum(acc) * (1.f / 64.f);
    float dv = acc - m;
    float var = waveAllSum(dv * dv) * (1.f / 64.f);
    xo[row * 64 + lane] = dv * rsqrtf(var + EPSF) * g2[lane] + b2[lane];
}

// K10: avg+max pool over l per (b,c)
__global__ __launch_bounds__(1024) void k_pool(const float* __restrict__ xo,
        float* __restrict__ pool) {
    __shared__ float ssum[16][64], smax[16][64];
    int b = blockIdx.x;
    int tid = threadIdx.x;
    int g = tid >> 6, c = tid & 63;
    float s = 0.f, m = -INFINITY;
    for (int l = g; l < LL; l += 16) {
        float v = xo[((long)b * LL + l) * 64 + c];
        s += v; m = fmaxf(m, v);
    }
    ssum[g][c] = s; smax[g][c] = m;
    __syncthreads();
    if (g == 0) {
        float S = 0.f, M = -INFINITY;
#pragma unroll
        for (int k = 0; k < 16; k++) { S += ssum[k][c]; M = fmaxf(M, smax[k][c]); }
        pool[b * 64 + c] = S * (1.f / LL);
        pool[128 + b * 64 + c] = M;
    }
}

// K11: channel attention
__global__ __launch_bounds__(128) void k_att(const float* __restrict__ pool,
        const float* __restrict__ w1, const float* __restrict__ w2,
        float* __restrict__ att) {
    __shared__ float hs[2][2][32];
    int tid = threadIdx.x;
    {
        int which = tid >> 6;
        int rb = tid & 63;
        int bb = rb >> 5, r = rb & 31;
        const float* v = pool + which * 128 + bb * 64;
        float a = 0.f;
        for (int c = 0; c < 64; c++) a += v[c] * w1[r * 64 + c];
        hs[which][bb][r] = fmaxf(a, 0.f);
    }
    __syncthreads();
    int bb = tid >> 6, c = tid & 63;
    float s = 0.f;
#pragma unroll
    for (int r = 0; r < 32; r++) s += (hs[0][bb][r] + hs[1][bb][r]) * w2[c * 32 + r];
    att[bb * 64 + c] = 1.f / (1.f + expf(-s));
}

// K12: out[b,c,t,h,w] = xo[b,l,c] * att[b,c]
__global__ void k_final(const float* __restrict__ xo, const float* __restrict__ att,
        float* __restrict__ out) {
    long idx = (long)blockIdx.x * blockDim.x + threadIdx.x;
    if (idx >= 2L * 64 * LL) return;
    int l = (int)(idx % LL);
    int c = (int)((idx / LL) & 63);
    int b = (int)(idx / (64L * LL));
    out[idx] = xo[((long)b * LL + l) * 64 + c] * att[b * 64 + c];
}

extern "C" void kernel_launch(void* const* d_in, const int* in_sizes, int n_in,
                              void* d_out, int out_size, void* d_ws, size_t ws_size,
                              hipStream_t stream) {
    const float* x     = (const float*)d_in[0];
    const float* tdc_w = (const float*)d_in[1];
    const float* bn_g  = (const float*)d_in[2];
    const float* bn_b  = (const float*)d_in[3];
    const float* bn_m  = (const float*)d_in[4];
    const float* bn_v  = (const float*)d_in[5];
    const float* ln1_g = (const float*)d_in[6];
    const float* ln1_b = (const float*)d_in[7];
    const float* ln2_g = (const float*)d_in[8];
    const float* ln2_b = (const float*)d_in[9];
    const float* ca_w1 = (const float*)d_in[10];
    const float* ca_w2 = (const float*)d_in[11];
    const float* f_in_w    = (const float*)d_in[12];
    const float* f_conv_w  = (const float*)d_in[13];
    const float* f_conv_b  = (const float*)d_in[14];
    const float* f_xproj_w = (const float*)d_in[15];
    const float* f_dt_w    = (const float*)d_in[16];
    const float* f_dt_b    = (const float*)d_in[17];
    const float* f_A_log   = (const float*)d_in[18];
    const float* f_D       = (const float*)d_in[19];
    const float* f_out_w   = (const float*)d_in[20];
    const float* b_in_w    = (const float*)d_in[21];
    const float* b_conv_w  = (const float*)d_in[22];
    const float* b_conv_b  = (const float*)d_in[23];
    const float* b_xproj_w = (const float*)d_in[24];
    const float* b_dt_w    = (const float*)d_in[25];
    const float* b_dt_b    = (const float*)d_in[26];
    const float* b_A_log   = (const float*)d_in[27];
    const float* b_D       = (const float*)d_in[28];
    const float* b_out_w   = (const float*)d_in[29];

    float* ws = (float*)d_ws;
    __bf16* wbf = (__bf16*)(ws + OFF_WEFF);
    float* xf   = ws + OFF_XF;
    float* xn   = ws + OFF_XN;
    float* xin  = ws + OFF_XIN;   // reused as yg after k_conv1d consumes it
    float* z    = ws + OFF_Z;
    float* xc   = ws + OFF_XC;
    float* dt   = ws + OFF_DT;
    float* Bm   = ws + OFF_BM;
    float* Cm   = ws + OFF_CM;
    float* csP  = ws + OFF_CSP;
    float* csS  = ws + OFF_CSS;
    float* xo   = ws + OFF_XO;
    float* pool = ws + OFF_POOL;
    float* att  = ws + OFF_ATT;
    float* yg   = xin;

    hipLaunchKernelGGL(k_fold, dim3(16), dim3(256), 0, stream, tdc_w, wbf);
    hipLaunchKernelGGL(k_conv3d_mfma, dim3(2 * TT * 2), dim3(256), 0, stream,
                       x, wbf, bn_g, bn_b, bn_m, bn_v, xf);
    hipLaunchKernelGGL(k_ln1, dim3(2 * LL / 4), dim3(256), 0, stream,
                       xf, ln1_g, ln1_b, xn);
    hipLaunchKernelGGL(k_xz, dim3(2 * LL / 8, 2), dim3(256), 0, stream,
                       xn, f_in_w, b_in_w, xin, z);
    hipLaunchKernelGGL(k_conv1d, dim3((2 * 2 * LL * DI) / 256), dim3(256), 0, stream,
                       xin, f_conv_w, f_conv_b, b_conv_w, b_conv_b, xc);
    hipLaunchKernelGGL(k_xproj, dim3(2 * LL / 16, 2), dim3(256), 0, stream,
                       xc, f_xproj_w, b_xproj_w, f_dt_w, f_dt_b, b_dt_w, b_dt_b,
                       dt, Bm, Cm);
    hipLaunchKernelGGL(k_scanA, dim3(NCH, 4), dim3(128), 0, stream,
                       dt, xc, Bm, f_A_log, b_A_log, csP, csS);
    hipLaunchKernelGGL(k_combine, dim3(32), dim3(256), 0, stream, csP, csS);
    hipLaunchKernelGGL(k_scanC, dim3(NCH, 4), dim3(128), 0, stream,
                       dt, xc, Bm, Cm, z, csS, f_A_log, b_A_log, f_D, b_D, yg);
    hipLaunchKernelGGL(k_outln, dim3(2 * LL / 4), dim3(256), 0, stream,
                       yg, xf, f_out_w, b_out_w, ln2_g, ln2_b, xo);
    hipLaunchKernelGGL(k_pool, dim3(2), dim3(1024), 0, stream, xo, pool);
    hipLaunchKernelGGL(k_att, dim3(1), dim3(128), 0, stream, pool, ca_w1, ca_w2, att);
    hipLaunchKernelGGL(k_final, dim3((2 * 64 * LL) / 256), dim3(256), 0, stream,
                       xo, att, (float*)d_out);
}

// Round 3
// 437.504 us; speedup vs baseline: 3.9273x; 1.5633x over previous
//
#include <hip/hip_runtime.h>
#include <math.h>

#define DI    128
#define DS16  16
#define LL    10240            // T*H*W = 160*64
#define TT    160
#define NCH   160              // scan chunks
#define CLEN  64               // chunk length (NCH*CLEN == LL)
#define THETA 0.5f
#define EPSF  1e-5f
#define XPAD  72               // padded c stride (bf16 el) for conv LDS tiles

typedef __bf16 bf16x8 __attribute__((ext_vector_type(8)));
typedef float  f32x4  __attribute__((ext_vector_type(4)));

// ---------------- workspace layout (floats) ----------------
#define OFF_WEFF  0L                      // bf16 conv weights: 27*64*72*2B
#define OFF_XF    (OFF_WEFF + 110592L)    // 2*L*64              = 1310720
#define OFF_XN    (OFF_XF   + 1310720L)   // reused: bf16 weights + pool partials
#define OFF_XIN   (OFF_XN   + 1310720L)   // 2dir*2b*L*128       = 5242880  (aliased as YG)
#define OFF_Z     (OFF_XIN  + 5242880L)
#define OFF_XC    (OFF_Z    + 5242880L)
#define OFF_DT    (OFF_XC   + 5242880L)
#define OFF_BM    (OFF_DT   + 5242880L)   // 2*2*L*16            = 655360
#define OFF_CM    (OFF_BM   + 655360L)
#define OFF_CSP   (OFF_CM   + 655360L)    // 2*2*160*2048        = 1310720
#define OFF_CSS   (OFF_CSP  + 1310720L)
#define OFF_XO    (OFF_CSS  + 1310720L)
#define OFF_POOL  (OFF_XO   + 1310720L)   // legacy (unused)
#define OFF_ATT   (OFF_POOL + 256L)       // 128

// sub-allocations inside the old XN region (floats)
#define OFF_WBX   OFF_XN                  // bf16 [dir][256][72]  = 18432 floats
#define OFF_WBO   (OFF_XN + 18432L)       // bf16 [dir][64][136]  = 8704 floats
#define OFF_PSUM  (OFF_XN + 27136L)       // [2][80][64]          = 10240 floats
#define OFF_PMAX  (OFF_PSUM + 10240L)     // [2][80][64]

__device__ inline float waveAllSum(float v) {
#pragma unroll
    for (int off = 32; off > 0; off >>= 1) v += __shfl_xor(v, off, 64);
    return v;
}

// K0: fold temporal-difference into conv weights; emit bf16 [k27][o][XPAD]
__global__ void k_fold(const float* __restrict__ w, __bf16* __restrict__ wbf) {
    int idx = blockIdx.x * blockDim.x + threadIdx.x;   // 4096 threads
    if (idx < 64 * 64) {
        int o = idx >> 6, c = idx & 63;
        const float* wb = w + (o * 64 + c) * 27;
        float kd = 0.f;
#pragma unroll
        for (int i = 0; i < 9; i++) kd += wb[i] + wb[18 + i];
#pragma unroll
        for (int k = 0; k < 27; k++) {
            float v = wb[k];
            if (k == 13) v -= THETA * kd;   // center tap (kt=1,kh=1,kw=1)
            wbf[((long)k * 64 + o) * XPAD + c] = (__bf16)v;
        }
    }
    for (int i = idx; i < 27 * 64 * 8; i += 4096) {
        int k = i >> 9;
        int rem = i & 511;
        int o = rem >> 3, j = rem & 7;
        wbf[((long)k * 64 + o) * XPAD + 64 + j] = (__bf16)0.f;
    }
}

// K0b: pre-convert in-proj / out-proj weights to padded bf16
__global__ void k_prep(const float* __restrict__ fw, const float* __restrict__ bw,
                       const float* __restrict__ fo, const float* __restrict__ bo,
                       __bf16* __restrict__ wbx, __bf16* __restrict__ wbo) {
    int idx = blockIdx.x * blockDim.x + threadIdx.x;
    if (idx < 2 * 256 * 72) {
        int c = idx % 72; int rest = idx / 72; int d = rest & 255; int dir = rest >> 8;
        const float* s = dir ? bw : fw;
        wbx[idx] = (c < 64) ? (__bf16)s[d * 64 + c] : (__bf16)0.f;
    }
    if (idx < 2 * 64 * 136) {
        int k = idx % 136; int rest = idx / 136; int o = rest & 63; int dir = rest >> 6;
        const float* s = dir ? bo : fo;
        wbo[idx] = (k < 128) ? (__bf16)s[o * 128 + k] : (__bf16)0.f;
    }
}

// K1: conv3d (+folded temp-diff) + BN + ReLU via bf16 MFMA -> xf [b][l][c]
__global__ __launch_bounds__(256) void k_conv3d_mfma(
        const float* __restrict__ x, const __bf16* __restrict__ wbf,
        const float* __restrict__ bn_g, const float* __restrict__ bn_b,
        const float* __restrict__ bn_m, const float* __restrict__ bn_v,
        float* __restrict__ xf) {
    __shared__ __align__(16) __bf16 Xs[100 * XPAD];      // 14400 B
    __shared__ __align__(16) __bf16 Wsh[9 * 32 * XPAD];  // 41472 B
    int blk = blockIdx.x;
    int oh = blk & 1;
    int bt = blk >> 1;
    int b = bt / TT, t = bt % TT;
    int tid = threadIdx.x;
    int wave = tid >> 6, lane = tid & 63;
    int lane15 = lane & 15, q4 = lane >> 4;
    int m0 = (wave & 1) * 32;
    int nsel = wave >> 1;

    int hw0 = m0 + lane15;
    int hw1 = m0 + 16 + lane15;
    int hA0 = hw0 >> 3, wA0 = hw0 & 7;
    int hA1 = hw1 >> 3, wA1 = hw1 & 7;

    f32x4 acc0 = {0.f, 0.f, 0.f, 0.f};
    f32x4 acc1 = {0.f, 0.f, 0.f, 0.f};

    for (int kt = 0; kt < 3; kt++) {
        __syncthreads();
        for (int i = tid; i < 100 * XPAD / 2; i += 256)
            ((unsigned int*)Xs)[i] = 0u;
        {
            const unsigned int* src = (const unsigned int*)wbf;
            unsigned int* dst = (unsigned int*)Wsh;
            for (int i = tid; i < 9 * 32 * 36; i += 256) {
                int tap = i / (32 * 36);
                int r = i - tap * (32 * 36);
                dst[tap * (32 * 36) + r] = src[((kt * 9 + tap) * 64 + oh * 32) * 36 + r];
            }
        }
        __syncthreads();
        int ts = t + kt - 1;
        if (ts >= 0 && ts < TT) {
            int hw = tid & 63;
            int h = hw >> 3, w = hw & 7;
            int row = (h + 1) * 10 + (w + 1);
            const float* xb = x + (((long)b * 64) * TT + ts) * 64 + hw;
#pragma unroll
            for (int i = 0; i < 8; i++) {
                int c2 = i * 8 + (tid >> 6) * 2;
                float v0 = xb[(long)c2 * TT * 64];
                float v1 = xb[(long)(c2 + 1) * TT * 64];
                union { unsigned int u; __bf16 h2[2]; } pk;
                pk.h2[0] = (__bf16)v0; pk.h2[1] = (__bf16)v1;
                ((unsigned int*)Xs)[row * (XPAD / 2) + (c2 >> 1)] = pk.u;
            }
        }
        __syncthreads();
#pragma unroll
        for (int kh = 0; kh < 3; kh++) {
#pragma unroll
            for (int kw = 0; kw < 3; kw++) {
                int tap = kh * 3 + kw;
                int r0 = (hA0 + kh) * 10 + (wA0 + kw);
                int r1 = (hA1 + kh) * 10 + (wA1 + kw);
                const __bf16* xp0 = &Xs[r0 * XPAD + q4 * 8];
                const __bf16* xp1 = &Xs[r1 * XPAD + q4 * 8];
                const __bf16* wp  = &Wsh[(tap * 32 + nsel * 16 + lane15) * XPAD + q4 * 8];
#pragma unroll
                for (int ch = 0; ch < 2; ch++) {
                    bf16x8 a0 = *(const bf16x8*)(xp0 + ch * 32);
                    bf16x8 a1 = *(const bf16x8*)(xp1 + ch * 32);
                    bf16x8 bb = *(const bf16x8*)(wp + ch * 32);
                    acc0 = __builtin_amdgcn_mfma_f32_16x16x32_bf16(a0, bb, acc0, 0, 0, 0);
                    acc1 = __builtin_amdgcn_mfma_f32_16x16x32_bf16(a1, bb, acc1, 0, 0, 0);
                }
            }
        }
    }
    int o = oh * 32 + nsel * 16 + lane15;
    float sc = bn_g[o] * rsqrtf(bn_v[o] + EPSF);
    float sh = bn_b[o] - bn_m[o] * sc;
    long obase = (long)b * LL + t * 64;
#pragma unroll
    for (int r = 0; r < 4; r++) {
        int hwr0 = m0 + q4 * 4 + r;
        int hwr1 = m0 + 16 + q4 * 4 + r;
        xf[(obase + hwr0) * 64 + o] = fmaxf(acc0[r] * sc + sh, 0.f);
        xf[(obase + hwr1) * 64 + o] = fmaxf(acc1[r] * sc + sh, 0.f);
    }
}

// K3: fused LN1 + in-proj GEMM via bf16 MFMA: xin, z  [dir][b][l][d]
// Block: 64 rows x 256 outputs, K=64. wave = m-tile.
__global__ __launch_bounds__(256) void k_xz_mfma(const float* __restrict__ xf,
        const __bf16* __restrict__ wbx,
        const float* __restrict__ ln1g, const float* __restrict__ ln1b,
        float* __restrict__ xin, float* __restrict__ z) {
    __shared__ __align__(16) __bf16 As[64 * 72];     // 9216 B
    __shared__ __align__(16) __bf16 Ws[256 * 72];    // 36864 B
    __shared__ float ps[64][4], ps2[64][4];
    __shared__ float sm[64], sr[64];
    int dir = blockIdx.y;
    int tid = threadIdx.x;
    long row0 = (long)blockIdx.x * 64;
    int b = (int)(row0 / LL);
    int l0 = (int)(row0 % LL);

    // load 16 fp32 per thread (row r, quarter q) + partial stats
    int r = tid >> 2, q = tid & 3;
    int ls = dir ? (LL - 1 - (l0 + r)) : (l0 + r);
    const float* srcx = xf + ((long)b * LL + ls) * 64 + q * 16;
    float v[16];
#pragma unroll
    for (int k = 0; k < 4; k++) {
        float4 t4 = ((const float4*)srcx)[k];
        v[k * 4 + 0] = t4.x; v[k * 4 + 1] = t4.y;
        v[k * 4 + 2] = t4.z; v[k * 4 + 3] = t4.w;
    }
    float s = 0.f, s2 = 0.f;
#pragma unroll
    for (int k = 0; k < 16; k++) { s += v[k]; s2 += v[k] * v[k]; }
    ps[r][q] = s; ps2[r][q] = s2;
    // stage W (bf16, straight dword copy)
    {
        const unsigned int* wsrc = (const unsigned int*)wbx + (long)dir * 256 * 36;
        unsigned int* wdst = (unsigned int*)Ws;
        for (int i = tid; i < 256 * 36; i += 256) wdst[i] = wsrc[i];
    }
    __syncthreads();
    if (tid < 64) {
        float ts = ps[tid][0] + ps[tid][1] + ps[tid][2] + ps[tid][3];
        float ts2 = ps2[tid][0] + ps2[tid][1] + ps2[tid][2] + ps2[tid][3];
        float m = ts * (1.f / 64.f);
        float var = ts2 * (1.f / 64.f) - m * m;
        sm[tid] = m; sr[tid] = rsqrtf(var + EPSF);
    }
    __syncthreads();
    {
        float m = sm[r], rs = sr[r];
        unsigned int* adst = (unsigned int*)As;
#pragma unroll
        for (int k = 0; k < 8; k++) {
            int c = q * 16 + k * 2;
            float a0 = (v[k * 2 + 0 + (k & 0) ] , 0.f); // placeholder avoided below
            (void)a0;
            float x0 = (v[2 * k] - m) * rs * ln1g[c] + ln1b[c];
            float x1 = (v[2 * k + 1] - m) * rs * ln1g[c + 1] + ln1b[c + 1];
            union { unsigned int u; __bf16 h[2]; } pk;
            pk.h[0] = (__bf16)x0; pk.h[1] = (__bf16)x1;
            adst[r * 36 + q * 8 + k] = pk.u;
        }
    }
    __syncthreads();

    int wv = tid >> 6, lane = tid & 63;
    int lane15 = lane & 15, q4 = lane >> 4;
    f32x4 acc[16];
#pragma unroll
    for (int i = 0; i < 16; i++) acc[i] = (f32x4){0.f, 0.f, 0.f, 0.f};
    int arow = wv * 16 + lane15;
#pragma unroll
    for (int ks = 0; ks < 2; ks++) {
        bf16x8 af = *(const bf16x8*)&As[arow * 72 + ks * 32 + q4 * 8];
#pragma unroll
        for (int nt = 0; nt < 16; nt++) {
            bf16x8 bfr = *(const bf16x8*)&Ws[(nt * 16 + lane15) * 72 + ks * 32 + q4 * 8];
            acc[nt] = __builtin_amdgcn_mfma_f32_16x16x32_bf16(af, bfr, acc[nt], 0, 0, 0);
        }
    }
    float* xinD = xin + (long)dir * 2 * LL * DI;
    float* zD   = z   + (long)dir * 2 * LL * DI;
#pragma unroll
    for (int nt = 0; nt < 16; nt++) {
        int d = nt * 16 + lane15;
        float* dst = (d < 128) ? (xinD + d) : (zD + d - 128);
#pragma unroll
        for (int reg = 0; reg < 4; reg++) {
            long R = row0 + wv * 16 + q4 * 4 + reg;
            dst[R * 128] = acc[nt][reg];
        }
    }
}

// K4: causal depthwise conv1d + silu -> xc
__global__ void k_conv1d(const float* __restrict__ xin,
        const float* __restrict__ cw_f, const float* __restrict__ cb_f,
        const float* __restrict__ cw_b, const float* __restrict__ cb_b,
        float* __restrict__ xc) {
    long idx = (long)blockIdx.x * blockDim.x + threadIdx.x;
    long total = 2L * 2 * LL * DI;
    if (idx >= total) return;
    int d = idx & 127;
    long rem = idx >> 7;
    int l = (int)(rem % LL);
    int bd = (int)(rem / LL);
    int dir = bd >> 1;
    const float* cw = dir ? cw_b : cw_f;
    const float* cb = dir ? cb_b : cb_f;
    const float* xbase = xin + (long)bd * LL * DI + d;
    float a = cb[d];
#pragma unroll
    for (int k = 0; k < 4; k++) {
        int ls = l + k - 3;
        if (ls >= 0) a += xbase[(long)ls * DI] * cw[d * 4 + k];
    }
    xc[idx] = a / (1.f + expf(-a));
}

// K5: x-proj + dt-proj + softplus -> dt, Bm, Cm
__global__ __launch_bounds__(256) void k_xproj(const float* __restrict__ xc,
        const float* __restrict__ xpw_f, const float* __restrict__ xpw_b,
        const float* __restrict__ dtw_f, const float* __restrict__ dtb_f,
        const float* __restrict__ dtw_b, const float* __restrict__ dtb_b,
        float* __restrict__ dt, float* __restrict__ Bm, float* __restrict__ Cm) {
    __shared__ float xcr[16 * 128];
    __shared__ float xpT[128 * 36];
    __shared__ float dbl[16 * 36];
    __shared__ float dtw[512];
    int dir = blockIdx.y;
    const float* xpw  = dir ? xpw_b : xpw_f;
    const float* dtwp = dir ? dtw_b : dtw_f;
    const float* dtbp = dir ? dtb_b : dtb_f;
    const float* xcD = xc + (long)dir * 2 * LL * DI;
    float* dtD = dt + (long)dir * 2 * LL * DI;
    float* BmD = Bm + (long)dir * 2 * LL * DS16;
    float* CmD = Cm + (long)dir * 2 * LL * DS16;
    int tid = threadIdx.x;
    long row0 = (long)blockIdx.x * 16;
    for (int i = tid; i < 16 * 128; i += 256) xcr[i] = xcD[row0 * 128 + i];
    for (int i = tid; i < 36 * 128; i += 256) {
        int e = i / 128, d = i & 127;
        xpT[d * 36 + e] = xpw[i];
    }
    for (int i = tid; i < 512; i += 256) dtw[i] = dtwp[i];
    __syncthreads();
    for (int i = tid; i < 576; i += 256) {
        int r = i / 36, e = i % 36;
        float a = 0.f;
        for (int d = 0; d < 128; d++) a += xcr[r * 128 + d] * xpT[d * 36 + e];
        dbl[r * 36 + e] = a;
    }
    __syncthreads();
    for (int i = tid; i < 2048; i += 256) {
        int r = i >> 7, d = i & 127;
        float a = dtbp[d];
#pragma unroll
        for (int k = 0; k < 4; k++) a += dbl[r * 36 + k] * dtw[d * 4 + k];
        float sp = fmaxf(a, 0.f) + log1pf(expf(-fabsf(a)));
        dtD[(row0 + r) * 128 + d] = sp;
    }
    for (int i = tid; i < 256; i += 256) {
        int r = i >> 4, s = i & 15;
        BmD[(row0 + r) * 16 + s] = dbl[r * 36 + 4 + s];
        CmD[(row0 + r) * 16 + s] = dbl[r * 36 + 20 + s];
    }
}

// K6: scan phase A — per-chunk (P = prod dA, S = local scan w/ h0=0)
__global__ __launch_bounds__(128) void k_scanA(const float* __restrict__ dt,
        const float* __restrict__ xc, const float* __restrict__ Bm,
        const float* __restrict__ Alog_f, const float* __restrict__ Alog_b,
        float* __restrict__ csP, float* __restrict__ csS) {
    int d = threadIdx.x;
    int chunk = blockIdx.x;
    int bd = blockIdx.y;
    const float* Alog = (bd >> 1) ? Alog_b : Alog_f;
    float ac[16], h[16], P[16];
#pragma unroll
    for (int s = 0; s < 16; s++) { ac[s] = -expf(Alog[d * 16 + s]); h[s] = 0.f; P[s] = 1.f; }
    long base = (long)bd * LL;
    int l0 = chunk * CLEN;
    const float* dtp = dt + (base + l0) * 128 + d;
    const float* xcp = xc + (base + l0) * 128 + d;
    const float* bmp = Bm + (base + l0) * 16;
    for (int l = 0; l < CLEN; l++) {
        float dtv = dtp[(long)l * 128];
        float dtx = dtv * xcp[(long)l * 128];
        const float* bl = bmp + l * 16;
#pragma unroll
        for (int s = 0; s < 16; s++) {
            float a = expf(dtv * ac[s]);
            h[s] = a * h[s] + dtx * bl[s];
            P[s] *= a;
        }
    }
    long cso = ((long)bd * NCH + chunk) * 2048 + d * 16;
#pragma unroll
    for (int s = 0; s < 16; s++) { csP[cso + s] = P[s]; csS[cso + s] = h[s]; }
}

// K7: sequential combine over chunks; csS[c] becomes h_in for chunk c
__global__ void k_combine(const float* __restrict__ csP, float* __restrict__ csS) {
    int idx = blockIdx.x * blockDim.x + threadIdx.x;  // 8192
    int bd = idx >> 11;
    int ds = idx & 2047;
    float hin = 0.f;
#pragma unroll 8
    for (int c = 0; c < NCH; c++) {
        long o = ((long)bd * NCH + c) * 2048 + ds;
        float P = csP[o], S = csS[o];
        csS[o] = hin;
        hin = P * hin + S;
    }
}

// K8: scan phase C — replay with h_in, emit y = (scan + D*xc)*silu(z)
__global__ __launch_bounds__(128) void k_scanC(const float* __restrict__ dt,
        const float* __restrict__ xc, const float* __restrict__ Bm,
        const float* __restrict__ Cm, const float* __restrict__ z,
        const float* __restrict__ csS,
        const float* __restrict__ Alog_f, const float* __restrict__ Alog_b,
        const float* __restrict__ D_f, const float* __restrict__ D_b,
        float* __restrict__ yg) {
    int d = threadIdx.x;
    int chunk = blockIdx.x;
    int bd = blockIdx.y;
    int dir = bd >> 1;
    const float* Alog = dir ? Alog_b : Alog_f;
    float Dv = dir ? D_b[d] : D_f[d];
    float ac[16], h[16];
    long cso = ((long)bd * NCH + chunk) * 2048 + d * 16;
#pragma unroll
    for (int s = 0; s < 16; s++) { ac[s] = -expf(Alog[d * 16 + s]); h[s] = csS[cso + s]; }
    long base = (long)bd * LL;
    int l0 = chunk * CLEN;
    const float* dtp = dt + (base + l0) * 128 + d;
    const float* xcp = xc + (base + l0) * 128 + d;
    const float* zp  = z  + (base + l0) * 128 + d;
    const float* bmp = Bm + (base + l0) * 16;
    const float* cmp = Cm + (base + l0) * 16;
    float* yp = yg + (base + l0) * 128 + d;
    for (int l = 0; l < CLEN; l++) {
        float dtv = dtp[(long)l * 128];
        float xcv = xcp[(long)l * 128];
        float dtx = dtv * xcv;
        const float* bl = bmp + l * 16;
        const float* cl = cmp + l * 16;
        float y = 0.f;
#pragma unroll
        for (int s = 0; s < 16; s++) {
            float a = expf(dtv * ac[s]);
            h[s] = a * h[s] + dtx * bl[s];
            y += h[s] * cl[s];
        }
        y += Dv * xcv;
        float zv = zp[(long)l * 128];
        y *= zv / (1.f + expf(-zv));
        yp[(long)l * 128] = y;
    }
}

// K9: out-proj (both dirs) + residual + in-register LN2 via bf16 MFMA -> xo
// Block: 64 rows x 64 outs, K = 2 x 128. wave = m-tile (owns full row -> shfl LN).
__global__ __launch_bounds__(256) void k_outln_mfma(const float* __restrict__ yg,
        const float* __restrict__ xf, const __bf16* __restrict__ wbo,
        const float* __restrict__ g2, const float* __restrict__ b2,
        float* __restrict__ xo) {
    __shared__ __align__(16) __bf16 As[64 * 136];   // 17408 B
    __shared__ __align__(16) __bf16 Bs[64 * 136];   // 17408 B
    int tid = threadIdx.x;
    long row0 = (long)blockIdx.x * 64;
    int b = (int)(row0 / LL);
    int l0 = (int)(row0 % LL);
    int wv = tid >> 6, lane = tid & 63, lane15 = lane & 15, q4 = lane >> 4;
    f32x4 acc[4];
#pragma unroll
    for (int i = 0; i < 4; i++) acc[i] = (f32x4){0.f, 0.f, 0.f, 0.f};

    for (int dir = 0; dir < 2; dir++) {
        __syncthreads();
        // stage A: 64 rows x 128 dd (bf16)
        int r = tid >> 2, q = tid & 3;
        int ls = dir ? (LL - 1 - (l0 + r)) : (l0 + r);
        const float* src = yg + ((long)(dir * 2 + b) * LL + ls) * 128 + q * 32;
        unsigned int* adst = (unsigned int*)As;
#pragma unroll
        for (int k = 0; k < 8; k++) {
            float4 t4 = ((const float4*)src)[k];
            union { unsigned int u; __bf16 h[2]; } p0, p1;
            p0.h[0] = (__bf16)t4.x; p0.h[1] = (__bf16)t4.y;
            p1.h[0] = (__bf16)t4.z; p1.h[1] = (__bf16)t4.w;
            adst[r * 68 + q * 16 + k * 2]     = p0.u;
            adst[r * 68 + q * 16 + k * 2 + 1] = p1.u;
        }
        // stage B
        const unsigned int* wsrc = (const unsigned int*)wbo + (long)dir * 64 * 68;
        unsigned int* bdst = (unsigned int*)Bs;
        for (int i = tid; i < 64 * 68; i += 256) bdst[i] = wsrc[i];
        __syncthreads();
        int arow = wv * 16 + lane15;
#pragma unroll
        for (int ks = 0; ks < 4; ks++) {
            bf16x8 af = *(const bf16x8*)&As[arow * 136 + ks * 32 + q4 * 8];
#pragma unroll
            for (int nt = 0; nt < 4; nt++) {
                bf16x8 bfr = *(const bf16x8*)&Bs[(nt * 16 + lane15) * 136 + ks * 32 + q4 * 8];
                acc[nt] = __builtin_amdgcn_mfma_f32_16x16x32_bf16(af, bfr, acc[nt], 0, 0, 0);
            }
        }
    }
    // epilogue: residual + LN over 64 c (in-register) + store
    float vals[4][4];
#pragma unroll
    for (int nt = 0; nt < 4; nt++) {
        int c = nt * 16 + lane15;
#pragma unroll
        for (int reg = 0; reg < 4; reg++) {
            long R = row0 + wv * 16 + q4 * 4 + reg;
            vals[nt][reg] = acc[nt][reg] + xf[R * 64 + c];
        }
    }
#pragma unroll
    for (int reg = 0; reg < 4; reg++) {
        float ssum = vals[0][reg] + vals[1][reg] + vals[2][reg] + vals[3][reg];
#pragma unroll
        for (int m = 1; m < 16; m <<= 1) ssum += __shfl_xor(ssum, m, 64);
        float mean = ssum * (1.f / 64.f);
        float vv = 0.f;
#pragma unroll
        for (int nt = 0; nt < 4; nt++) { float dd = vals[nt][reg] - mean; vv += dd * dd; }
#pragma unroll
        for (int m = 1; m < 16; m <<= 1) vv += __shfl_xor(vv, m, 64);
        float rs = rsqrtf(vv * (1.f / 64.f) + EPSF);
        long R = row0 + wv * 16 + q4 * 4 + reg;
#pragma unroll
        for (int nt = 0; nt < 4; nt++) {
            int c = nt * 16 + lane15;
            xo[R * 64 + c] = (vals[nt][reg] - mean) * rs * g2[c] + b2[c];
        }
    }
}

// K10a: pool stage-1 partials over 128-row slices
__global__ __launch_bounds__(256) void k_pool1(const float* __restrict__ xo,
        float* __restrict__ psum, float* __restrict__ pmax) {
    __shared__ float ss[4][64], sx[4][64];
    int b = blockIdx.x, s = blockIdx.y;
    int tid = threadIdx.x;
    int g = tid >> 6, c = tid & 63;
    float sum = 0.f, mx = -INFINITY;
    const float* base = xo + ((long)b * LL + s * 128) * 64 + c;
    for (int r = g; r < 128; r += 4) {
        float v = base[(long)r * 64];
        sum += v; mx = fmaxf(mx, v);
    }
    ss[g][c] = sum; sx[g][c] = mx;
    __syncthreads();
    if (g == 0) {
        float S = ss[0][c] + ss[1][c] + ss[2][c] + ss[3][c];
        float M = fmaxf(fmaxf(sx[0][c], sx[1][c]), fmaxf(sx[2][c], sx[3][c]));
        psum[(b * 80 + s) * 64 + c] = S;
        pmax[(b * 80 + s) * 64 + c] = M;
    }
}

// K11: pool combine + channel attention
__global__ __launch_bounds__(128) void k_att2(const float* __restrict__ psum,
        const float* __restrict__ pmax,
        const float* __restrict__ w1, const float* __restrict__ w2,
        float* __restrict__ att) {
    __shared__ float pav[2][64], pmx[2][64];
    __shared__ float hs[2][2][32];
    int tid = threadIdx.x;
    {
        int bb = tid >> 6, c = tid & 63;
        float S = 0.f, M = -INFINITY;
#pragma unroll 8
        for (int s = 0; s < 80; s++) {
            S += psum[(bb * 80 + s) * 64 + c];
            M = fmaxf(M, pmax[(bb * 80 + s) * 64 + c]);
        }
        pav[bb][c] = S * (1.f / LL);
        pmx[bb][c] = M;
    }
    __syncthreads();
    {
        int which = tid >> 6, rb = tid & 63, bb = rb >> 5, rr = rb & 31;
        const float* v = which ? pmx[bb] : pav[bb];
        float a = 0.f;
        for (int c = 0; c < 64; c++) a += v[c] * w1[rr * 64 + c];
        hs[which][bb][rr] = fmaxf(a, 0.f);
    }
    __syncthreads();
    int bb = tid >> 6, c = tid & 63;
    float sv = 0.f;
#pragma unroll
    for (int rr = 0; rr < 32; rr++) sv += (hs[0][bb][rr] + hs[1][bb][rr]) * w2[c * 32 + rr];
    att[bb * 64 + c] = 1.f / (1.f + expf(-sv));
}

// K12: out[b,c,t,h,w] = xo[b,l,c] * att[b,c]
__global__ void k_final(const float* __restrict__ xo, const float* __restrict__ att,
        float* __restrict__ out) {
    long idx = (long)blockIdx.x * blockDim.x + threadIdx.x;
    if (idx >= 2L * 64 * LL) return;
    int l = (int)(idx % LL);
    int c = (int)((idx / LL) & 63);
    int b = (int)(idx / (64L * LL));
    out[idx] = xo[((long)b * LL + l) * 64 + c] * att[b * 64 + c];
}

extern "C" void kernel_launch(void* const* d_in, const int* in_sizes, int n_in,
                              void* d_out, int out_size, void* d_ws, size_t ws_size,
                              hipStream_t stream) {
    const float* x     = (const float*)d_in[0];
    const float* tdc_w = (const float*)d_in[1];
    const float* bn_g  = (const float*)d_in[2];
    const float* bn_b  = (const float*)d_in[3];
    const float* bn_m  = (const float*)d_in[4];
    const float* bn_v  = (const float*)d_in[5];
    const float* ln1_g = (const float*)d_in[6];
    const float* ln1_b = (const float*)d_in[7];
    const float* ln2_g = (const float*)d_in[8];
    const float* ln2_b = (const float*)d_in[9];
    const float* ca_w1 = (const float*)d_in[10];
    const float* ca_w2 = (const float*)d_in[11];
    const float* f_in_w    = (const float*)d_in[12];
    const float* f_conv_w  = (const float*)d_in[13];
    const float* f_conv_b  = (const float*)d_in[14];
    const float* f_xproj_w = (const float*)d_in[15];
    const float* f_dt_w    = (const float*)d_in[16];
    const float* f_dt_b    = (const float*)d_in[17];
    const float* f_A_log   = (const float*)d_in[18];
    const float* f_D       = (const float*)d_in[19];
    const float* f_out_w   = (const float*)d_in[20];
    const float* b_in_w    = (const float*)d_in[21];
    const float* b_conv_w  = (const float*)d_in[22];
    const float* b_conv_b  = (const float*)d_in[23];
    const float* b_xproj_w = (const float*)d_in[24];
    const float* b_dt_w    = (const float*)d_in[25];
    const float* b_dt_b    = (const float*)d_in[26];
    const float* b_A_log   = (const float*)d_in[27];
    const float* b_D       = (const float*)d_in[28];
    const float* b_out_w   = (const float*)d_in[29];

    float* ws = (float*)d_ws;
    __bf16* wbf = (__bf16*)(ws + OFF_WEFF);
    float* xf   = ws + OFF_XF;
    __bf16* wbx = (__bf16*)(ws + OFF_WBX);
    __bf16* wbo = (__bf16*)(ws + OFF_WBO);
    float* psum = ws + OFF_PSUM;
    float* pmax = ws + OFF_PMAX;
    float* xin  = ws + OFF_XIN;   // reused as yg after k_conv1d consumes it
    float* z    = ws + OFF_Z;
    float* xc   = ws + OFF_XC;
    float* dt   = ws + OFF_DT;
    float* Bm   = ws + OFF_BM;
    float* Cm   = ws + OFF_CM;
    float* csP  = ws + OFF_CSP;
    float* csS  = ws + OFF_CSS;
    float* xo   = ws + OFF_XO;
    float* att  = ws + OFF_ATT;
    float* yg   = xin;

    hipLaunchKernelGGL(k_fold, dim3(16), dim3(256), 0, stream, tdc_w, wbf);
    hipLaunchKernelGGL(k_prep, dim3(144), dim3(256), 0, stream,
                       f_in_w, b_in_w, f_out_w, b_out_w, wbx, wbo);
    hipLaunchKernelGGL(k_conv3d_mfma, dim3(2 * TT * 2), dim3(256), 0, stream,
                       x, wbf, bn_g, bn_b, bn_m, bn_v, xf);
    hipLaunchKernelGGL(k_xz_mfma, dim3(2 * LL / 64, 2), dim3(256), 0, stream,
                       xf, wbx, ln1_g, ln1_b, xin, z);
    hipLaunchKernelGGL(k_conv1d, dim3((2 * 2 * LL * DI) / 256), dim3(256), 0, stream,
                       xin, f_conv_w, f_conv_b, b_conv_w, b_conv_b, xc);
    hipLaunchKernelGGL(k_xproj, dim3(2 * LL / 16, 2), dim3(256), 0, stream,
                       xc, f_xproj_w, b_xproj_w, f_dt_w, f_dt_b, b_dt_w, b_dt_b,
                       dt, Bm, Cm);
    hipLaunchKernelGGL(k_scanA, dim3(NCH, 4), dim3(128), 0, stream,
                       dt, xc, Bm, f_A_log, b_A_log, csP, csS);
    hipLaunchKernelGGL(k_combine, dim3(32), dim3(256), 0, stream, csP, csS);
    hipLaunchKernelGGL(k_scanC, dim3(NCH, 4), dim3(128), 0, stream,
                       dt, xc, Bm, Cm, z, csS, f_A_log, b_A_log, f_D, b_D, yg);
    hipLaunchKernelGGL(k_outln_mfma, dim3(2 * LL / 64), dim3(256), 0, stream,
                       yg, xf, wbo, ln2_g, ln2_b, xo);
    hipLaunchKernelGGL(k_pool1, dim3(2, 80), dim3(256), 0, stream, xo, psum, pmax);
    hipLaunchKernelGGL(k_att2, dim3(1), dim3(128), 0, stream, psum, pmax, ca_w1, ca_w2, att);
    hipLaunchKernelGGL(k_final, dim3((2 * 64 * LL) / 256), dim3(256), 0, stream,
                       xo, att, (float*)d_out);
}

// Round 4
// 337.847 us; speedup vs baseline: 5.0857x; 1.2950x over previous
//
#include <hip/hip_runtime.h>
#include <math.h>

#define DI    128
#define DS16  16
#define LL    10240            // T*H*W = 160*64
#define TT    160
#define NCH   160              // scan chunks
#define CLEN  64               // chunk length (NCH*CLEN == LL)
#define THETA 0.5f
#define EPSF  1e-5f
#define XPAD  72               // padded c stride (bf16 el) for conv LDS tiles

typedef __bf16 bf16x8 __attribute__((ext_vector_type(8)));
typedef float  f32x4  __attribute__((ext_vector_type(4)));

// ---------------- workspace layout (floats) ----------------
#define OFF_WEFF  0L                      // bf16 conv weights: 27*64*72*2B
#define OFF_XF    (OFF_WEFF + 110592L)    // 2*L*64              = 1310720
#define OFF_XN    (OFF_XF   + 1310720L)   // reused: bf16 weights + pool partials
#define OFF_XIN   (OFF_XN   + 1310720L)   // 2dir*2b*L*128       = 5242880  (aliased as YG)
#define OFF_Z     (OFF_XIN  + 5242880L)
#define OFF_XC    (OFF_Z    + 5242880L)
#define OFF_DT    (OFF_XC   + 5242880L)
#define OFF_BM    (OFF_DT   + 5242880L)   // 2*2*L*16            = 655360
#define OFF_CM    (OFF_BM   + 655360L)
#define OFF_CSP   (OFF_CM   + 655360L)    // 2*2*160*2048        = 1310720
#define OFF_CSS   (OFF_CSP  + 1310720L)
#define OFF_XO    (OFF_CSS  + 1310720L)
#define OFF_POOL  (OFF_XO   + 1310720L)   // legacy (unused)
#define OFF_ATT   (OFF_POOL + 256L)       // 128

// sub-allocations inside the old XN region (floats)
#define OFF_WBX   OFF_XN                  // bf16 [dir][256][72]  = 18432 floats
#define OFF_WBO   (OFF_XN + 18432L)       // bf16 [dir][64][136]  = 8704 floats
#define OFF_PSUM  (OFF_XN + 27136L)       // [2][80][64]          = 10240 floats
#define OFF_PMAX  (OFF_PSUM + 10240L)     // [2][80][64]

__device__ inline float waveAllSum(float v) {
#pragma unroll
    for (int off = 32; off > 0; off >>= 1) v += __shfl_xor(v, off, 64);
    return v;
}

// K0: fold temporal-difference into conv weights; emit bf16 [k27][o][XPAD]
__global__ void k_fold(const float* __restrict__ w, __bf16* __restrict__ wbf) {
    int idx = blockIdx.x * blockDim.x + threadIdx.x;   // 4096 threads
    if (idx < 64 * 64) {
        int o = idx >> 6, c = idx & 63;
        const float* wb = w + (o * 64 + c) * 27;
        float kd = 0.f;
#pragma unroll
        for (int i = 0; i < 9; i++) kd += wb[i] + wb[18 + i];
#pragma unroll
        for (int k = 0; k < 27; k++) {
            float v = wb[k];
            if (k == 13) v -= THETA * kd;   // center tap (kt=1,kh=1,kw=1)
            wbf[((long)k * 64 + o) * XPAD + c] = (__bf16)v;
        }
    }
    for (int i = idx; i < 27 * 64 * 8; i += 4096) {
        int k = i >> 9;
        int rem = i & 511;
        int o = rem >> 3, j = rem & 7;
        wbf[((long)k * 64 + o) * XPAD + 64 + j] = (__bf16)0.f;
    }
}

// K0b: pre-convert in-proj / out-proj weights to padded bf16
__global__ void k_prep(const float* __restrict__ fw, const float* __restrict__ bw,
                       const float* __restrict__ fo, const float* __restrict__ bo,
                       __bf16* __restrict__ wbx, __bf16* __restrict__ wbo) {
    int idx = blockIdx.x * blockDim.x + threadIdx.x;
    if (idx < 2 * 256 * 72) {
        int c = idx % 72; int rest = idx / 72; int d = rest & 255; int dir = rest >> 8;
        const float* s = dir ? bw : fw;
        wbx[idx] = (c < 64) ? (__bf16)s[d * 64 + c] : (__bf16)0.f;
    }
    if (idx < 2 * 64 * 136) {
        int k = idx % 136; int rest = idx / 136; int o = rest & 63; int dir = rest >> 6;
        const float* s = dir ? bo : fo;
        wbo[idx] = (k < 128) ? (__bf16)s[o * 128 + k] : (__bf16)0.f;
    }
}

// K1: conv3d (+folded temp-diff) + BN + ReLU via bf16 MFMA -> xf [b][l][c]
__global__ __launch_bounds__(256) void k_conv3d_mfma(
        const float* __restrict__ x, const __bf16* __restrict__ wbf,
        const float* __restrict__ bn_g, const float* __restrict__ bn_b,
        const float* __restrict__ bn_m, const float* __restrict__ bn_v,
        float* __restrict__ xf) {
    __shared__ __align__(16) __bf16 Xs[100 * XPAD];      // 14400 B
    __shared__ __align__(16) __bf16 Wsh[9 * 32 * XPAD];  // 41472 B
    int blk = blockIdx.x;
    int oh = blk & 1;
    int bt = blk >> 1;
    int b = bt / TT, t = bt % TT;
    int tid = threadIdx.x;
    int wave = tid >> 6, lane = tid & 63;
    int lane15 = lane & 15, q4 = lane >> 4;
    int m0 = (wave & 1) * 32;
    int nsel = wave >> 1;

    int hw0 = m0 + lane15;
    int hw1 = m0 + 16 + lane15;
    int hA0 = hw0 >> 3, wA0 = hw0 & 7;
    int hA1 = hw1 >> 3, wA1 = hw1 & 7;

    f32x4 acc0 = {0.f, 0.f, 0.f, 0.f};
    f32x4 acc1 = {0.f, 0.f, 0.f, 0.f};

    for (int kt = 0; kt < 3; kt++) {
        __syncthreads();
        for (int i = tid; i < 100 * XPAD / 2; i += 256)
            ((unsigned int*)Xs)[i] = 0u;
        {
            const unsigned int* src = (const unsigned int*)wbf;
            unsigned int* dst = (unsigned int*)Wsh;
            for (int i = tid; i < 9 * 32 * 36; i += 256) {
                int tap = i / (32 * 36);
                int r = i - tap * (32 * 36);
                dst[tap * (32 * 36) + r] = src[((kt * 9 + tap) * 64 + oh * 32) * 36 + r];
            }
        }
        __syncthreads();
        int ts = t + kt - 1;
        if (ts >= 0 && ts < TT) {
            int hw = tid & 63;
            int h = hw >> 3, w = hw & 7;
            int row = (h + 1) * 10 + (w + 1);
            const float* xb = x + (((long)b * 64) * TT + ts) * 64 + hw;
#pragma unroll
            for (int i = 0; i < 8; i++) {
                int c2 = i * 8 + (tid >> 6) * 2;
                float v0 = xb[(long)c2 * TT * 64];
                float v1 = xb[(long)(c2 + 1) * TT * 64];
                union { unsigned int u; __bf16 h2[2]; } pk;
                pk.h2[0] = (__bf16)v0; pk.h2[1] = (__bf16)v1;
                ((unsigned int*)Xs)[row * (XPAD / 2) + (c2 >> 1)] = pk.u;
            }
        }
        __syncthreads();
#pragma unroll
        for (int kh = 0; kh < 3; kh++) {
#pragma unroll
            for (int kw = 0; kw < 3; kw++) {
                int tap = kh * 3 + kw;
                int r0 = (hA0 + kh) * 10 + (wA0 + kw);
                int r1 = (hA1 + kh) * 10 + (wA1 + kw);
                const __bf16* xp0 = &Xs[r0 * XPAD + q4 * 8];
                const __bf16* xp1 = &Xs[r1 * XPAD + q4 * 8];
                const __bf16* wp  = &Wsh[(tap * 32 + nsel * 16 + lane15) * XPAD + q4 * 8];
#pragma unroll
                for (int ch = 0; ch < 2; ch++) {
                    bf16x8 a0 = *(const bf16x8*)(xp0 + ch * 32);
                    bf16x8 a1 = *(const bf16x8*)(xp1 + ch * 32);
                    bf16x8 bb = *(const bf16x8*)(wp + ch * 32);
                    acc0 = __builtin_amdgcn_mfma_f32_16x16x32_bf16(a0, bb, acc0, 0, 0, 0);
                    acc1 = __builtin_amdgcn_mfma_f32_16x16x32_bf16(a1, bb, acc1, 0, 0, 0);
                }
            }
        }
    }
    int o = oh * 32 + nsel * 16 + lane15;
    float sc = bn_g[o] * rsqrtf(bn_v[o] + EPSF);
    float sh = bn_b[o] - bn_m[o] * sc;
    long obase = (long)b * LL + t * 64;
#pragma unroll
    for (int r = 0; r < 4; r++) {
        int hwr0 = m0 + q4 * 4 + r;
        int hwr1 = m0 + 16 + q4 * 4 + r;
        xf[(obase + hwr0) * 64 + o] = fmaxf(acc0[r] * sc + sh, 0.f);
        xf[(obase + hwr1) * 64 + o] = fmaxf(acc1[r] * sc + sh, 0.f);
    }
}

// K3: fused LN1 + in-proj GEMM via bf16 MFMA: xin, z  [dir][b][l][d]
__global__ __launch_bounds__(256) void k_xz_mfma(const float* __restrict__ xf,
        const __bf16* __restrict__ wbx,
        const float* __restrict__ ln1g, const float* __restrict__ ln1b,
        float* __restrict__ xin, float* __restrict__ z) {
    __shared__ __align__(16) __bf16 As[64 * 72];     // 9216 B
    __shared__ __align__(16) __bf16 Ws[256 * 72];    // 36864 B
    __shared__ float ps[64][4], ps2[64][4];
    __shared__ float sm[64], sr[64];
    int dir = blockIdx.y;
    int tid = threadIdx.x;
    long row0 = (long)blockIdx.x * 64;
    int b = (int)(row0 / LL);
    int l0 = (int)(row0 % LL);

    int r = tid >> 2, q = tid & 3;
    int ls = dir ? (LL - 1 - (l0 + r)) : (l0 + r);
    const float* srcx = xf + ((long)b * LL + ls) * 64 + q * 16;
    float v[16];
#pragma unroll
    for (int k = 0; k < 4; k++) {
        float4 t4 = ((const float4*)srcx)[k];
        v[k * 4 + 0] = t4.x; v[k * 4 + 1] = t4.y;
        v[k * 4 + 2] = t4.z; v[k * 4 + 3] = t4.w;
    }
    float s = 0.f, s2 = 0.f;
#pragma unroll
    for (int k = 0; k < 16; k++) { s += v[k]; s2 += v[k] * v[k]; }
    ps[r][q] = s; ps2[r][q] = s2;
    {
        const unsigned int* wsrc = (const unsigned int*)wbx + (long)dir * 256 * 36;
        unsigned int* wdst = (unsigned int*)Ws;
        for (int i = tid; i < 256 * 36; i += 256) wdst[i] = wsrc[i];
    }
    __syncthreads();
    if (tid < 64) {
        float ts = ps[tid][0] + ps[tid][1] + ps[tid][2] + ps[tid][3];
        float ts2 = ps2[tid][0] + ps2[tid][1] + ps2[tid][2] + ps2[tid][3];
        float m = ts * (1.f / 64.f);
        float var = ts2 * (1.f / 64.f) - m * m;
        sm[tid] = m; sr[tid] = rsqrtf(var + EPSF);
    }
    __syncthreads();
    {
        float m = sm[r], rs = sr[r];
        unsigned int* adst = (unsigned int*)As;
#pragma unroll
        for (int k = 0; k < 8; k++) {
            int c = q * 16 + k * 2;
            float x0 = (v[2 * k] - m) * rs * ln1g[c] + ln1b[c];
            float x1 = (v[2 * k + 1] - m) * rs * ln1g[c + 1] + ln1b[c + 1];
            union { unsigned int u; __bf16 h[2]; } pk;
            pk.h[0] = (__bf16)x0; pk.h[1] = (__bf16)x1;
            adst[r * 36 + q * 8 + k] = pk.u;
        }
    }
    __syncthreads();

    int wv = tid >> 6, lane = tid & 63;
    int lane15 = lane & 15, q4 = lane >> 4;
    f32x4 acc[16];
#pragma unroll
    for (int i = 0; i < 16; i++) acc[i] = (f32x4){0.f, 0.f, 0.f, 0.f};
    int arow = wv * 16 + lane15;
#pragma unroll
    for (int ks = 0; ks < 2; ks++) {
        bf16x8 af = *(const bf16x8*)&As[arow * 72 + ks * 32 + q4 * 8];
#pragma unroll
        for (int nt = 0; nt < 16; nt++) {
            bf16x8 bfr = *(const bf16x8*)&Ws[(nt * 16 + lane15) * 72 + ks * 32 + q4 * 8];
            acc[nt] = __builtin_amdgcn_mfma_f32_16x16x32_bf16(af, bfr, acc[nt], 0, 0, 0);
        }
    }
    float* xinD = xin + (long)dir * 2 * LL * DI;
    float* zD   = z   + (long)dir * 2 * LL * DI;
#pragma unroll
    for (int nt = 0; nt < 16; nt++) {
        int d = nt * 16 + lane15;
        float* dst = (d < 128) ? (xinD + d) : (zD + d - 128);
#pragma unroll
        for (int reg = 0; reg < 4; reg++) {
            long R = row0 + wv * 16 + q4 * 4 + reg;
            dst[R * 128] = acc[nt][reg];
        }
    }
}

// K4: causal depthwise conv1d + silu -> xc
__global__ void k_conv1d(const float* __restrict__ xin,
        const float* __restrict__ cw_f, const float* __restrict__ cb_f,
        const float* __restrict__ cw_b, const float* __restrict__ cb_b,
        float* __restrict__ xc) {
    long idx = (long)blockIdx.x * blockDim.x + threadIdx.x;
    long total = 2L * 2 * LL * DI;
    if (idx >= total) return;
    int d = idx & 127;
    long rem = idx >> 7;
    int l = (int)(rem % LL);
    int bd = (int)(rem / LL);
    int dir = bd >> 1;
    const float* cw = dir ? cw_b : cw_f;
    const float* cb = dir ? cb_b : cb_f;
    const float* xbase = xin + (long)bd * LL * DI + d;
    float a = cb[d];
#pragma unroll
    for (int k = 0; k < 4; k++) {
        int ls = l + k - 3;
        if (ls >= 0) a += xbase[(long)ls * DI] * cw[d * 4 + k];
    }
    xc[idx] = a / (1.f + __expf(-a));
}

// K5: x-proj + dt-proj + softplus -> dt, Bm, Cm
__global__ __launch_bounds__(256) void k_xproj(const float* __restrict__ xc,
        const float* __restrict__ xpw_f, const float* __restrict__ xpw_b,
        const float* __restrict__ dtw_f, const float* __restrict__ dtb_f,
        const float* __restrict__ dtw_b, const float* __restrict__ dtb_b,
        float* __restrict__ dt, float* __restrict__ Bm, float* __restrict__ Cm) {
    __shared__ float xcr[16 * 128];
    __shared__ float xpT[128 * 36];
    __shared__ float dbl[16 * 36];
    __shared__ float dtw[512];
    int dir = blockIdx.y;
    const float* xpw  = dir ? xpw_b : xpw_f;
    const float* dtwp = dir ? dtw_b : dtw_f;
    const float* dtbp = dir ? dtb_b : dtb_f;
    const float* xcD = xc + (long)dir * 2 * LL * DI;
    float* dtD = dt + (long)dir * 2 * LL * DI;
    float* BmD = Bm + (long)dir * 2 * LL * DS16;
    float* CmD = Cm + (long)dir * 2 * LL * DS16;
    int tid = threadIdx.x;
    long row0 = (long)blockIdx.x * 16;
    for (int i = tid; i < 16 * 128; i += 256) xcr[i] = xcD[row0 * 128 + i];
    for (int i = tid; i < 36 * 128; i += 256) {
        int e = i / 128, d = i & 127;
        xpT[d * 36 + e] = xpw[i];
    }
    for (int i = tid; i < 512; i += 256) dtw[i] = dtwp[i];
    __syncthreads();
    for (int i = tid; i < 576; i += 256) {
        int r = i / 36, e = i % 36;
        float a = 0.f;
        for (int d = 0; d < 128; d++) a += xcr[r * 128 + d] * xpT[d * 36 + e];
        dbl[r * 36 + e] = a;
    }
    __syncthreads();
    for (int i = tid; i < 2048; i += 256) {
        int r = i >> 7, d = i & 127;
        float a = dtbp[d];
#pragma unroll
        for (int k = 0; k < 4; k++) a += dbl[r * 36 + k] * dtw[d * 4 + k];
        float sp = fmaxf(a, 0.f) + log1pf(__expf(-fabsf(a)));
        dtD[(row0 + r) * 128 + d] = sp;
    }
    for (int i = tid; i < 256; i += 256) {
        int r = i >> 4, s = i & 15;
        BmD[(row0 + r) * 16 + s] = dbl[r * 36 + 4 + s];
        CmD[(row0 + r) * 16 + s] = dbl[r * 36 + 20 + s];
    }
}

// K6: scan phase A — per-chunk (P = prod dA, S = local scan w/ h0=0)
// 256 threads: sh = tid>>7 (s-half), d = tid&127. 8 states/thread. Prefetched.
__global__ __launch_bounds__(256) void k_scanA(const float* __restrict__ dt,
        const float* __restrict__ xc, const float* __restrict__ Bm,
        const float* __restrict__ Alog_f, const float* __restrict__ Alog_b,
        float* __restrict__ csP, float* __restrict__ csS) {
    int tid = threadIdx.x;
    int d = tid & 127, sh = tid >> 7;
    int chunk = blockIdx.x;
    int bd = blockIdx.y;                 // dir*2+b
    const float* Alog = (bd >> 1) ? Alog_b : Alog_f;
    float ac[8], h[8], P[8];
#pragma unroll
    for (int s = 0; s < 8; s++) {
        ac[s] = -__expf(Alog[d * 16 + sh * 8 + s]);
        h[s] = 0.f; P[s] = 1.f;
    }
    long base = (long)bd * LL;
    int l0 = chunk * CLEN;
    const float* dtp = dt + (base + l0) * 128 + d;
    const float* xcp = xc + (base + l0) * 128 + d;
    const float* bmp = Bm + (base + l0) * 16 + sh * 8;
    // prefetch l=0
    float dc = dtp[0], xcc = xcp[0];
    float4 b0c = *(const float4*)(bmp);
    float4 b1c = *(const float4*)(bmp + 4);
    for (int l = 0; l < CLEN; l++) {
        int ln = (l + 1 < CLEN) ? (l + 1) : l;
        float dn = dtp[(long)ln * 128];
        float xn_ = xcp[(long)ln * 128];
        float4 b0n = *(const float4*)(bmp + (long)ln * 16);
        float4 b1n = *(const float4*)(bmp + (long)ln * 16 + 4);
        float dtx = dc * xcc;
        float bb[8] = {b0c.x, b0c.y, b0c.z, b0c.w, b1c.x, b1c.y, b1c.z, b1c.w};
#pragma unroll
        for (int s = 0; s < 8; s++) {
            float a = __expf(dc * ac[s]);
            h[s] = a * h[s] + dtx * bb[s];
            P[s] *= a;
        }
        dc = dn; xcc = xn_; b0c = b0n; b1c = b1n;
    }
    long cso = ((long)bd * NCH + chunk) * 2048 + d * 16 + sh * 8;
    *(float4*)(csP + cso)     = (float4){P[0], P[1], P[2], P[3]};
    *(float4*)(csP + cso + 4) = (float4){P[4], P[5], P[6], P[7]};
    *(float4*)(csS + cso)     = (float4){h[0], h[1], h[2], h[3]};
    *(float4*)(csS + cso + 4) = (float4){h[4], h[5], h[6], h[7]};
}

// K7: sequential combine over chunks; csS[c] becomes h_in for chunk c
__global__ void k_combine(const float* __restrict__ csP, float* __restrict__ csS) {
    int idx = blockIdx.x * blockDim.x + threadIdx.x;  // 8192
    int bd = idx >> 11;
    int ds = idx & 2047;
    float hin = 0.f;
#pragma unroll 8
    for (int c = 0; c < NCH; c++) {
        long o = ((long)bd * NCH + c) * 2048 + ds;
        float P = csP[o], S = csS[o];
        csS[o] = hin;
        hin = P * hin + S;
    }
}

// K8: scan phase C — replay with h_in, emit y = (scan + D*xc)*silu(z)
// 256 threads: d = tid>>1, sh = tid&1. Lane-pair shfl reduce for y. Prefetched.
__global__ __launch_bounds__(256) void k_scanC(const float* __restrict__ dt,
        const float* __restrict__ xc, const float* __restrict__ Bm,
        const float* __restrict__ Cm, const float* __restrict__ z,
        const float* __restrict__ csS,
        const float* __restrict__ Alog_f, const float* __restrict__ Alog_b,
        const float* __restrict__ D_f, const float* __restrict__ D_b,
        float* __restrict__ yg) {
    int tid = threadIdx.x;
    int d = tid >> 1, sh = tid & 1;
    int chunk = blockIdx.x;
    int bd = blockIdx.y;
    int dir = bd >> 1;
    const float* Alog = dir ? Alog_b : Alog_f;
    float Dv = dir ? D_b[d] : D_f[d];
    float ac[8], h[8];
    long cso = ((long)bd * NCH + chunk) * 2048 + d * 16 + sh * 8;
    {
        float4 h0 = *(const float4*)(csS + cso);
        float4 h1 = *(const float4*)(csS + cso + 4);
        h[0] = h0.x; h[1] = h0.y; h[2] = h0.z; h[3] = h0.w;
        h[4] = h1.x; h[5] = h1.y; h[6] = h1.z; h[7] = h1.w;
    }
#pragma unroll
    for (int s = 0; s < 8; s++) ac[s] = -__expf(Alog[d * 16 + sh * 8 + s]);
    long base = (long)bd * LL;
    int l0 = chunk * CLEN;
    const float* dtp = dt + (base + l0) * 128 + d;
    const float* xcp = xc + (base + l0) * 128 + d;
    const float* zp  = z  + (base + l0) * 128 + d;
    const float* bmp = Bm + (base + l0) * 16 + sh * 8;
    const float* cmp = Cm + (base + l0) * 16 + sh * 8;
    float* yp = yg + (base + l0) * 128 + d;
    // prefetch l=0
    float dc = dtp[0], xcc = xcp[0], zc = zp[0];
    float4 b0c = *(const float4*)(bmp);
    float4 b1c = *(const float4*)(bmp + 4);
    float4 c0c = *(const float4*)(cmp);
    float4 c1c = *(const float4*)(cmp + 4);
    for (int l = 0; l < CLEN; l++) {
        int ln = (l + 1 < CLEN) ? (l + 1) : l;
        float dn = dtp[(long)ln * 128];
        float xn_ = xcp[(long)ln * 128];
        float zn = zp[(long)ln * 128];
        float4 b0n = *(const float4*)(bmp + (long)ln * 16);
        float4 b1n = *(const float4*)(bmp + (long)ln * 16 + 4);
        float4 c0n = *(const float4*)(cmp + (long)ln * 16);
        float4 c1n = *(const float4*)(cmp + (long)ln * 16 + 4);
        float dtx = dc * xcc;
        float bb[8] = {b0c.x, b0c.y, b0c.z, b0c.w, b1c.x, b1c.y, b1c.z, b1c.w};
        float cc[8] = {c0c.x, c0c.y, c0c.z, c0c.w, c1c.x, c1c.y, c1c.z, c1c.w};
        float y = 0.f;
#pragma unroll
        for (int s = 0; s < 8; s++) {
            float a = __expf(dc * ac[s]);
            h[s] = a * h[s] + dtx * bb[s];
            y += h[s] * cc[s];
        }
        y += __shfl_xor(y, 1, 64);
        if (sh == 0) {
            y += Dv * xcc;
            y *= zc / (1.f + __expf(-zc));
            yp[(long)l * 128] = y;
        }
        dc = dn; xcc = xn_; zc = zn;
        b0c = b0n; b1c = b1n; c0c = c0n; c1c = c1n;
    }
}

// K9: out-proj (both dirs) + residual + in-register LN2 via bf16 MFMA -> xo
__global__ __launch_bounds__(256) void k_outln_mfma(const float* __restrict__ yg,
        const float* __restrict__ xf, const __bf16* __restrict__ wbo,
        const float* __restrict__ g2, const float* __restrict__ b2,
        float* __restrict__ xo) {
    __shared__ __align__(16) __bf16 As[64 * 136];   // 17408 B
    __shared__ __align__(16) __bf16 Bs[64 * 136];   // 17408 B
    int tid = threadIdx.x;
    long row0 = (long)blockIdx.x * 64;
    int b = (int)(row0 / LL);
    int l0 = (int)(row0 % LL);
    int wv = tid >> 6, lane = tid & 63, lane15 = lane & 15, q4 = lane >> 4;
    f32x4 acc[4];
#pragma unroll
    for (int i = 0; i < 4; i++) acc[i] = (f32x4){0.f, 0.f, 0.f, 0.f};

    for (int dir = 0; dir < 2; dir++) {
        __syncthreads();
        int r = tid >> 2, q = tid & 3;
        int ls = dir ? (LL - 1 - (l0 + r)) : (l0 + r);
        const float* src = yg + ((long)(dir * 2 + b) * LL + ls) * 128 + q * 32;
        unsigned int* adst = (unsigned int*)As;
#pragma unroll
        for (int k = 0; k < 8; k++) {
            float4 t4 = ((const float4*)src)[k];
            union { unsigned int u; __bf16 h[2]; } p0, p1;
            p0.h[0] = (__bf16)t4.x; p0.h[1] = (__bf16)t4.y;
            p1.h[0] = (__bf16)t4.z; p1.h[1] = (__bf16)t4.w;
            adst[r * 68 + q * 16 + k * 2]     = p0.u;
            adst[r * 68 + q * 16 + k * 2 + 1] = p1.u;
        }
        const unsigned int* wsrc = (const unsigned int*)wbo + (long)dir * 64 * 68;
        unsigned int* bdst = (unsigned int*)Bs;
        for (int i = tid; i < 64 * 68; i += 256) bdst[i] = wsrc[i];
        __syncthreads();
        int arow = wv * 16 + lane15;
#pragma unroll
        for (int ks = 0; ks < 4; ks++) {
            bf16x8 af = *(const bf16x8*)&As[arow * 136 + ks * 32 + q4 * 8];
#pragma unroll
            for (int nt = 0; nt < 4; nt++) {
                bf16x8 bfr = *(const bf16x8*)&Bs[(nt * 16 + lane15) * 136 + ks * 32 + q4 * 8];
                acc[nt] = __builtin_amdgcn_mfma_f32_16x16x32_bf16(af, bfr, acc[nt], 0, 0, 0);
            }
        }
    }
    float vals[4][4];
#pragma unroll
    for (int nt = 0; nt < 4; nt++) {
        int c = nt * 16 + lane15;
#pragma unroll
        for (int reg = 0; reg < 4; reg++) {
            long R = row0 + wv * 16 + q4 * 4 + reg;
            vals[nt][reg] = acc[nt][reg] + xf[R * 64 + c];
        }
    }
#pragma unroll
    for (int reg = 0; reg < 4; reg++) {
        float ssum = vals[0][reg] + vals[1][reg] + vals[2][reg] + vals[3][reg];
#pragma unroll
        for (int m = 1; m < 16; m <<= 1) ssum += __shfl_xor(ssum, m, 64);
        float mean = ssum * (1.f / 64.f);
        float vv = 0.f;
#pragma unroll
        for (int nt = 0; nt < 4; nt++) { float dd = vals[nt][reg] - mean; vv += dd * dd; }
#pragma unroll
        for (int m = 1; m < 16; m <<= 1) vv += __shfl_xor(vv, m, 64);
        float rs = rsqrtf(vv * (1.f / 64.f) + EPSF);
        long R = row0 + wv * 16 + q4 * 4 + reg;
#pragma unroll
        for (int nt = 0; nt < 4; nt++) {
            int c = nt * 16 + lane15;
            xo[R * 64 + c] = (vals[nt][reg] - mean) * rs * g2[c] + b2[c];
        }
    }
}

// K10a: pool stage-1 partials over 128-row slices
__global__ __launch_bounds__(256) void k_pool1(const float* __restrict__ xo,
        float* __restrict__ psum, float* __restrict__ pmax) {
    __shared__ float ss[4][64], sx[4][64];
    int b = blockIdx.x, s = blockIdx.y;
    int tid = threadIdx.x;
    int g = tid >> 6, c = tid & 63;
    float sum = 0.f, mx = -INFINITY;
    const float* base = xo + ((long)b * LL + s * 128) * 64 + c;
    for (int r = g; r < 128; r += 4) {
        float v = base[(long)r * 64];
        sum += v; mx = fmaxf(mx, v);
    }
    ss[g][c] = sum; sx[g][c] = mx;
    __syncthreads();
    if (g == 0) {
        float S = ss[0][c] + ss[1][c] + ss[2][c] + ss[3][c];
        float M = fmaxf(fmaxf(sx[0][c], sx[1][c]), fmaxf(sx[2][c], sx[3][c]));
        psum[(b * 80 + s) * 64 + c] = S;
        pmax[(b * 80 + s) * 64 + c] = M;
    }
}

// K11: pool combine + channel attention
__global__ __launch_bounds__(128) void k_att2(const float* __restrict__ psum,
        const float* __restrict__ pmax,
        const float* __restrict__ w1, const float* __restrict__ w2,
        float* __restrict__ att) {
    __shared__ float pav[2][64], pmx[2][64];
    __shared__ float hs[2][2][32];
    int tid = threadIdx.x;
    {
        int bb = tid >> 6, c = tid & 63;
        float S = 0.f, M = -INFINITY;
#pragma unroll 8
        for (int s = 0; s < 80; s++) {
            S += psum[(bb * 80 + s) * 64 + c];
            M = fmaxf(M, pmax[(bb * 80 + s) * 64 + c]);
        }
        pav[bb][c] = S * (1.f / LL);
        pmx[bb][c] = M;
    }
    __syncthreads();
    {
        int which = tid >> 6, rb = tid & 63, bb = rb >> 5, rr = rb & 31;
        const float* v = which ? pmx[bb] : pav[bb];
        float a = 0.f;
        for (int c = 0; c < 64; c++) a += v[c] * w1[rr * 64 + c];
        hs[which][bb][rr] = fmaxf(a, 0.f);
    }
    __syncthreads();
    int bb = tid >> 6, c = tid & 63;
    float sv = 0.f;
#pragma unroll
    for (int rr = 0; rr < 32; rr++) sv += (hs[0][bb][rr] + hs[1][bb][rr]) * w2[c * 32 + rr];
    att[bb * 64 + c] = 1.f / (1.f + __expf(-sv));
}

// K12: out[b,c,t,h,w] = xo[b,l,c] * att[b,c]  — LDS-transposed, coalesced both ways
__global__ __launch_bounds__(256) void k_final2(const float* __restrict__ xo,
        const float* __restrict__ att, float* __restrict__ out) {
    __shared__ float tile[64][65];
    int b = blockIdx.y;
    int l0 = blockIdx.x * 64;
    int tid = threadIdx.x;
    int g = tid >> 6, lane = tid & 63;
    for (int rr = g; rr < 64; rr += 4)
        tile[rr][lane] = xo[((long)b * LL + l0 + rr) * 64 + lane];
    __syncthreads();
    for (int c = g; c < 64; c += 4) {
        float av = att[b * 64 + c];
        out[((long)(b * 64 + c)) * LL + l0 + lane] = tile[lane][c] * av;
    }
}

extern "C" void kernel_launch(void* const* d_in, const int* in_sizes, int n_in,
                              void* d_out, int out_size, void* d_ws, size_t ws_size,
                              hipStream_t stream) {
    const float* x     = (const float*)d_in[0];
    const float* tdc_w = (const float*)d_in[1];
    const float* bn_g  = (const float*)d_in[2];
    const float* bn_b  = (const float*)d_in[3];
    const float* bn_m  = (const float*)d_in[4];
    const float* bn_v  = (const float*)d_in[5];
    const float* ln1_g = (const float*)d_in[6];
    const float* ln1_b = (const float*)d_in[7];
    const float* ln2_g = (const float*)d_in[8];
    const float* ln2_b = (const float*)d_in[9];
    const float* ca_w1 = (const float*)d_in[10];
    const float* ca_w2 = (const float*)d_in[11];
    const float* f_in_w    = (const float*)d_in[12];
    const float* f_conv_w  = (const float*)d_in[13];
    const float* f_conv_b  = (const float*)d_in[14];
    const float* f_xproj_w = (const float*)d_in[15];
    const float* f_dt_w    = (const float*)d_in[16];
    const float* f_dt_b    = (const float*)d_in[17];
    const float* f_A_log   = (const float*)d_in[18];
    const float* f_D       = (const float*)d_in[19];
    const float* f_out_w   = (const float*)d_in[20];
    const float* b_in_w    = (const float*)d_in[21];
    const float* b_conv_w  = (const float*)d_in[22];
    const float* b_conv_b  = (const float*)d_in[23];
    const float* b_xproj_w = (const float*)d_in[24];
    const float* b_dt_w    = (const float*)d_in[25];
    const float* b_dt_b    = (const float*)d_in[26];
    const float* b_A_log   = (const float*)d_in[27];
    const float* b_D       = (const float*)d_in[28];
    const float* b_out_w   = (const float*)d_in[29];

    float* ws = (float*)d_ws;
    __bf16* wbf = (__bf16*)(ws + OFF_WEFF);
    float* xf   = ws + OFF_XF;
    __bf16* wbx = (__bf16*)(ws + OFF_WBX);
    __bf16* wbo = (__bf16*)(ws + OFF_WBO);
    float* psum = ws + OFF_PSUM;
    float* pmax = ws + OFF_PMAX;
    float* xin  = ws + OFF_XIN;   // reused as yg after k_conv1d consumes it
    float* z    = ws + OFF_Z;
    float* xc   = ws + OFF_XC;
    float* dt   = ws + OFF_DT;
    float* Bm   = ws + OFF_BM;
    float* Cm   = ws + OFF_CM;
    float* csP  = ws + OFF_CSP;
    float* csS  = ws + OFF_CSS;
    float* xo   = ws + OFF_XO;
    float* att  = ws + OFF_ATT;
    float* yg   = xin;

    hipLaunchKernelGGL(k_fold, dim3(16), dim3(256), 0, stream, tdc_w, wbf);
    hipLaunchKernelGGL(k_prep, dim3(144), dim3(256), 0, stream,
                       f_in_w, b_in_w, f_out_w, b_out_w, wbx, wbo);
    hipLaunchKernelGGL(k_conv3d_mfma, dim3(2 * TT * 2), dim3(256), 0, stream,
                       x, wbf, bn_g, bn_b, bn_m, bn_v, xf);
    hipLaunchKernelGGL(k_xz_mfma, dim3(2 * LL / 64, 2), dim3(256), 0, stream,
                       xf, wbx, ln1_g, ln1_b, xin, z);
    hipLaunchKernelGGL(k_conv1d, dim3((2 * 2 * LL * DI) / 256), dim3(256), 0, stream,
                       xin, f_conv_w, f_conv_b, b_conv_w, b_conv_b, xc);
    hipLaunchKernelGGL(k_xproj, dim3(2 * LL / 16, 2), dim3(256), 0, stream,
                       xc, f_xproj_w, b_xproj_w, f_dt_w, f_dt_b, b_dt_w, b_dt_b,
                       dt, Bm, Cm);
    hipLaunchKernelGGL(k_scanA, dim3(NCH, 4), dim3(256), 0, stream,
                       dt, xc, Bm, f_A_log, b_A_log, csP, csS);
    hipLaunchKernelGGL(k_combine, dim3(32), dim3(256), 0, stream, csP, csS);
    hipLaunchKernelGGL(k_scanC, dim3(NCH, 4), dim3(256), 0, stream,
                       dt, xc, Bm, Cm, z, csS, f_A_log, b_A_log, f_D, b_D, yg);
    hipLaunchKernelGGL(k_outln_mfma, dim3(2 * LL / 64), dim3(256), 0, stream,
                       yg, xf, wbo, ln2_g, ln2_b, xo);
    hipLaunchKernelGGL(k_pool1, dim3(2, 80), dim3(256), 0, stream, xo, psum, pmax);
    hipLaunchKernelGGL(k_att2, dim3(1), dim3(128), 0, stream, psum, pmax, ca_w1, ca_w2, att);
    hipLaunchKernelGGL(k_final2, dim3(160, 2), dim3(256), 0, stream,
                       xo, att, (float*)d_out);
}

// Round 5
// 336.333 us; speedup vs baseline: 5.1086x; 1.0045x over previous
//
#include <hip/hip_runtime.h>
#include <math.h>

#define DI    128
#define DS16  16
#define LL    10240            // T*H*W = 160*64
#define TT    160
#define NCH   160              // scan chunks
#define CLEN  64               // chunk length (NCH*CLEN == LL)
#define THETA 0.5f
#define EPSF  1e-5f
#define XPAD  72               // padded c stride (bf16 el) for conv LDS tiles

typedef __bf16 bf16x8 __attribute__((ext_vector_type(8)));
typedef float  f32x4  __attribute__((ext_vector_type(4)));

// ---------------- workspace layout (floats) ----------------
#define OFF_WEFF  0L                      // bf16 conv weights: 27*64*72*2B
#define OFF_XF    (OFF_WEFF + 110592L)    // 2*L*64              = 1310720
#define OFF_XN    (OFF_XF   + 1310720L)   // reused: bf16 weights + pool partials
#define OFF_XIN   (OFF_XN   + 1310720L)   // 2dir*2b*L*128       = 5242880  (aliased as YG)
#define OFF_Z     (OFF_XIN  + 5242880L)
#define OFF_XC    (OFF_Z    + 5242880L)
#define OFF_DT    (OFF_XC   + 5242880L)
#define OFF_BM    (OFF_DT   + 5242880L)   // 2*2*L*16            = 655360
#define OFF_CM    (OFF_BM   + 655360L)
#define OFF_CSP   (OFF_CM   + 655360L)    // 2*2*160*2048        = 1310720
#define OFF_CSS   (OFF_CSP  + 1310720L)
#define OFF_XO    (OFF_CSS  + 1310720L)
#define OFF_POOL  (OFF_XO   + 1310720L)   // legacy (unused)
#define OFF_ATT   (OFF_POOL + 256L)       // 128

// sub-allocations inside the old XN region (floats)
#define OFF_WBX   OFF_XN                  // bf16 [dir][256][72]  = 18432 floats
#define OFF_WBO   (OFF_XN + 18432L)       // bf16 [dir][64][136]  = 8704 floats
#define OFF_PSUM  (OFF_XN + 27136L)       // [2][80][64]          = 10240 floats
#define OFF_PMAX  (OFF_PSUM + 10240L)     // [2][80][64]

__device__ inline float waveAllSum(float v) {
#pragma unroll
    for (int off = 32; off > 0; off >>= 1) v += __shfl_xor(v, off, 64);
    return v;
}

// K0: fold temporal-difference into conv weights; emit bf16 [k27][o][XPAD]
__global__ void k_fold(const float* __restrict__ w, __bf16* __restrict__ wbf) {
    int idx = blockIdx.x * blockDim.x + threadIdx.x;   // 4096 threads
    if (idx < 64 * 64) {
        int o = idx >> 6, c = idx & 63;
        const float* wb = w + (o * 64 + c) * 27;
        float kd = 0.f;
#pragma unroll
        for (int i = 0; i < 9; i++) kd += wb[i] + wb[18 + i];
#pragma unroll
        for (int k = 0; k < 27; k++) {
            float v = wb[k];
            if (k == 13) v -= THETA * kd;   // center tap (kt=1,kh=1,kw=1)
            wbf[((long)k * 64 + o) * XPAD + c] = (__bf16)v;
        }
    }
    for (int i = idx; i < 27 * 64 * 8; i += 4096) {
        int k = i >> 9;
        int rem = i & 511;
        int o = rem >> 3, j = rem & 7;
        wbf[((long)k * 64 + o) * XPAD + 64 + j] = (__bf16)0.f;
    }
}

// K0b: pre-convert in-proj / out-proj weights to padded bf16
__global__ void k_prep(const float* __restrict__ fw, const float* __restrict__ bw,
                       const float* __restrict__ fo, const float* __restrict__ bo,
                       __bf16* __restrict__ wbx, __bf16* __restrict__ wbo) {
    int idx = blockIdx.x * blockDim.x + threadIdx.x;
    if (idx < 2 * 256 * 72) {
        int c = idx % 72; int rest = idx / 72; int d = rest & 255; int dir = rest >> 8;
        const float* s = dir ? bw : fw;
        wbx[idx] = (c < 64) ? (__bf16)s[d * 64 + c] : (__bf16)0.f;
    }
    if (idx < 2 * 64 * 136) {
        int k = idx % 136; int rest = idx / 136; int o = rest & 63; int dir = rest >> 6;
        const float* s = dir ? bo : fo;
        wbo[idx] = (k < 128) ? (__bf16)s[o * 128 + k] : (__bf16)0.f;
    }
}

// K1: conv3d (+folded temp-diff) + BN + ReLU via bf16 MFMA -> xf [b][l][c]
__global__ __launch_bounds__(256) void k_conv3d_mfma(
        const float* __restrict__ x, const __bf16* __restrict__ wbf,
        const float* __restrict__ bn_g, const float* __restrict__ bn_b,
        const float* __restrict__ bn_m, const float* __restrict__ bn_v,
        float* __restrict__ xf) {
    __shared__ __align__(16) __bf16 Xs[100 * XPAD];      // 14400 B
    __shared__ __align__(16) __bf16 Wsh[9 * 32 * XPAD];  // 41472 B
    int blk = blockIdx.x;
    int oh = blk & 1;
    int bt = blk >> 1;
    int b = bt / TT, t = bt % TT;
    int tid = threadIdx.x;
    int wave = tid >> 6, lane = tid & 63;
    int lane15 = lane & 15, q4 = lane >> 4;
    int m0 = (wave & 1) * 32;
    int nsel = wave >> 1;

    int hw0 = m0 + lane15;
    int hw1 = m0 + 16 + lane15;
    int hA0 = hw0 >> 3, wA0 = hw0 & 7;
    int hA1 = hw1 >> 3, wA1 = hw1 & 7;

    f32x4 acc0 = {0.f, 0.f, 0.f, 0.f};
    f32x4 acc1 = {0.f, 0.f, 0.f, 0.f};

    for (int kt = 0; kt < 3; kt++) {
        __syncthreads();
        for (int i = tid; i < 100 * XPAD / 2; i += 256)
            ((unsigned int*)Xs)[i] = 0u;
        {
            const unsigned int* src = (const unsigned int*)wbf;
            unsigned int* dst = (unsigned int*)Wsh;
            for (int i = tid; i < 9 * 32 * 36; i += 256) {
                int tap = i / (32 * 36);
                int r = i - tap * (32 * 36);
                dst[tap * (32 * 36) + r] = src[((kt * 9 + tap) * 64 + oh * 32) * 36 + r];
            }
        }
        __syncthreads();
        int ts = t + kt - 1;
        if (ts >= 0 && ts < TT) {
            int hw = tid & 63;
            int h = hw >> 3, w = hw & 7;
            int row = (h + 1) * 10 + (w + 1);
            const float* xb = x + (((long)b * 64) * TT + ts) * 64 + hw;
#pragma unroll
            for (int i = 0; i < 8; i++) {
                int c2 = i * 8 + (tid >> 6) * 2;
                float v0 = xb[(long)c2 * TT * 64];
                float v1 = xb[(long)(c2 + 1) * TT * 64];
                union { unsigned int u; __bf16 h2[2]; } pk;
                pk.h2[0] = (__bf16)v0; pk.h2[1] = (__bf16)v1;
                ((unsigned int*)Xs)[row * (XPAD / 2) + (c2 >> 1)] = pk.u;
            }
        }
        __syncthreads();
#pragma unroll
        for (int kh = 0; kh < 3; kh++) {
#pragma unroll
            for (int kw = 0; kw < 3; kw++) {
                int tap = kh * 3 + kw;
                int r0 = (hA0 + kh) * 10 + (wA0 + kw);
                int r1 = (hA1 + kh) * 10 + (wA1 + kw);
                const __bf16* xp0 = &Xs[r0 * XPAD + q4 * 8];
                const __bf16* xp1 = &Xs[r1 * XPAD + q4 * 8];
                const __bf16* wp  = &Wsh[(tap * 32 + nsel * 16 + lane15) * XPAD + q4 * 8];
#pragma unroll
                for (int ch = 0; ch < 2; ch++) {
                    bf16x8 a0 = *(const bf16x8*)(xp0 + ch * 32);
                    bf16x8 a1 = *(const bf16x8*)(xp1 + ch * 32);
                    bf16x8 bb = *(const bf16x8*)(wp + ch * 32);
                    acc0 = __builtin_amdgcn_mfma_f32_16x16x32_bf16(a0, bb, acc0, 0, 0, 0);
                    acc1 = __builtin_amdgcn_mfma_f32_16x16x32_bf16(a1, bb, acc1, 0, 0, 0);
                }
            }
        }
    }
    int o = oh * 32 + nsel * 16 + lane15;
    float sc = bn_g[o] * rsqrtf(bn_v[o] + EPSF);
    float sh = bn_b[o] - bn_m[o] * sc;
    long obase = (long)b * LL + t * 64;
#pragma unroll
    for (int r = 0; r < 4; r++) {
        int hwr0 = m0 + q4 * 4 + r;
        int hwr1 = m0 + 16 + q4 * 4 + r;
        xf[(obase + hwr0) * 64 + o] = fmaxf(acc0[r] * sc + sh, 0.f);
        xf[(obase + hwr1) * 64 + o] = fmaxf(acc1[r] * sc + sh, 0.f);
    }
}

// K3: fused LN1 + in-proj GEMM via bf16 MFMA: xin, z  [dir][b][l][d]
__global__ __launch_bounds__(256) void k_xz_mfma(const float* __restrict__ xf,
        const __bf16* __restrict__ wbx,
        const float* __restrict__ ln1g, const float* __restrict__ ln1b,
        float* __restrict__ xin, float* __restrict__ z) {
    __shared__ __align__(16) __bf16 As[64 * 72];     // 9216 B
    __shared__ __align__(16) __bf16 Ws[256 * 72];    // 36864 B
    __shared__ float ps[64][4], ps2[64][4];
    __shared__ float sm[64], sr[64];
    int dir = blockIdx.y;
    int tid = threadIdx.x;
    long row0 = (long)blockIdx.x * 64;
    int b = (int)(row0 / LL);
    int l0 = (int)(row0 % LL);

    int r = tid >> 2, q = tid & 3;
    int ls = dir ? (LL - 1 - (l0 + r)) : (l0 + r);
    const float* srcx = xf + ((long)b * LL + ls) * 64 + q * 16;
    float v[16];
#pragma unroll
    for (int k = 0; k < 4; k++) {
        float4 t4 = ((const float4*)srcx)[k];
        v[k * 4 + 0] = t4.x; v[k * 4 + 1] = t4.y;
        v[k * 4 + 2] = t4.z; v[k * 4 + 3] = t4.w;
    }
    float s = 0.f, s2 = 0.f;
#pragma unroll
    for (int k = 0; k < 16; k++) { s += v[k]; s2 += v[k] * v[k]; }
    ps[r][q] = s; ps2[r][q] = s2;
    {
        const unsigned int* wsrc = (const unsigned int*)wbx + (long)dir * 256 * 36;
        unsigned int* wdst = (unsigned int*)Ws;
        for (int i = tid; i < 256 * 36; i += 256) wdst[i] = wsrc[i];
    }
    __syncthreads();
    if (tid < 64) {
        float ts = ps[tid][0] + ps[tid][1] + ps[tid][2] + ps[tid][3];
        float ts2 = ps2[tid][0] + ps2[tid][1] + ps2[tid][2] + ps2[tid][3];
        float m = ts * (1.f / 64.f);
        float var = ts2 * (1.f / 64.f) - m * m;
        sm[tid] = m; sr[tid] = rsqrtf(var + EPSF);
    }
    __syncthreads();
    {
        float m = sm[r], rs = sr[r];
        unsigned int* adst = (unsigned int*)As;
#pragma unroll
        for (int k = 0; k < 8; k++) {
            int c = q * 16 + k * 2;
            float x0 = (v[2 * k] - m) * rs * ln1g[c] + ln1b[c];
            float x1 = (v[2 * k + 1] - m) * rs * ln1g[c + 1] + ln1b[c + 1];
            union { unsigned int u; __bf16 h[2]; } pk;
            pk.h[0] = (__bf16)x0; pk.h[1] = (__bf16)x1;
            adst[r * 36 + q * 8 + k] = pk.u;
        }
    }
    __syncthreads();

    int wv = tid >> 6, lane = tid & 63;
    int lane15 = lane & 15, q4 = lane >> 4;
    f32x4 acc[16];
#pragma unroll
    for (int i = 0; i < 16; i++) acc[i] = (f32x4){0.f, 0.f, 0.f, 0.f};
    int arow = wv * 16 + lane15;
#pragma unroll
    for (int ks = 0; ks < 2; ks++) {
        bf16x8 af = *(const bf16x8*)&As[arow * 72 + ks * 32 + q4 * 8];
#pragma unroll
        for (int nt = 0; nt < 16; nt++) {
            bf16x8 bfr = *(const bf16x8*)&Ws[(nt * 16 + lane15) * 72 + ks * 32 + q4 * 8];
            acc[nt] = __builtin_amdgcn_mfma_f32_16x16x32_bf16(af, bfr, acc[nt], 0, 0, 0);
        }
    }
    float* xinD = xin + (long)dir * 2 * LL * DI;
    float* zD   = z   + (long)dir * 2 * LL * DI;
#pragma unroll
    for (int nt = 0; nt < 16; nt++) {
        int d = nt * 16 + lane15;
        float* dst = (d < 128) ? (xinD + d) : (zD + d - 128);
#pragma unroll
        for (int reg = 0; reg < 4; reg++) {
            long R = row0 + wv * 16 + q4 * 4 + reg;
            dst[R * 128] = acc[nt][reg];
        }
    }
}

// K4: causal depthwise conv1d + silu -> xc
__global__ void k_conv1d(const float* __restrict__ xin,
        const float* __restrict__ cw_f, const float* __restrict__ cb_f,
        const float* __restrict__ cw_b, const float* __restrict__ cb_b,
        float* __restrict__ xc) {
    long idx = (long)blockIdx.x * blockDim.x + threadIdx.x;
    long total = 2L * 2 * LL * DI;
    if (idx >= total) return;
    int d = idx & 127;
    long rem = idx >> 7;
    int l = (int)(rem % LL);
    int bd = (int)(rem / LL);
    int dir = bd >> 1;
    const float* cw = dir ? cw_b : cw_f;
    const float* cb = dir ? cb_b : cb_f;
    const float* xbase = xin + (long)bd * LL * DI + d;
    float a = cb[d];
#pragma unroll
    for (int k = 0; k < 4; k++) {
        int ls = l + k - 3;
        if (ls >= 0) a += xbase[(long)ls * DI] * cw[d * 4 + k];
    }
    xc[idx] = a / (1.f + __expf(-a));
}

// K5: x-proj + dt-proj + softplus -> dt, Bm, Cm
__global__ __launch_bounds__(256) void k_xproj(const float* __restrict__ xc,
        const float* __restrict__ xpw_f, const float* __restrict__ xpw_b,
        const float* __restrict__ dtw_f, const float* __restrict__ dtb_f,
        const float* __restrict__ dtw_b, const float* __restrict__ dtb_b,
        float* __restrict__ dt, float* __restrict__ Bm, float* __restrict__ Cm) {
    __shared__ float xcr[16 * 128];
    __shared__ float xpT[128 * 36];
    __shared__ float dbl[16 * 36];
    __shared__ float dtw[512];
    int dir = blockIdx.y;
    const float* xpw  = dir ? xpw_b : xpw_f;
    const float* dtwp = dir ? dtw_b : dtw_f;
    const float* dtbp = dir ? dtb_b : dtb_f;
    const float* xcD = xc + (long)dir * 2 * LL * DI;
    float* dtD = dt + (long)dir * 2 * LL * DI;
    float* BmD = Bm + (long)dir * 2 * LL * DS16;
    float* CmD = Cm + (long)dir * 2 * LL * DS16;
    int tid = threadIdx.x;
    long row0 = (long)blockIdx.x * 16;
    for (int i = tid; i < 16 * 128; i += 256) xcr[i] = xcD[row0 * 128 + i];
    for (int i = tid; i < 36 * 128; i += 256) {
        int e = i / 128, d = i & 127;
        xpT[d * 36 + e] = xpw[i];
    }
    for (int i = tid; i < 512; i += 256) dtw[i] = dtwp[i];
    __syncthreads();
    for (int i = tid; i < 576; i += 256) {
        int r = i / 36, e = i % 36;
        float a = 0.f;
        for (int d = 0; d < 128; d++) a += xcr[r * 128 + d] * xpT[d * 36 + e];
        dbl[r * 36 + e] = a;
    }
    __syncthreads();
    for (int i = tid; i < 2048; i += 256) {
        int r = i >> 7, d = i & 127;
        float a = dtbp[d];
#pragma unroll
        for (int k = 0; k < 4; k++) a += dbl[r * 36 + k] * dtw[d * 4 + k];
        float sp = fmaxf(a, 0.f) + log1pf(__expf(-fabsf(a)));
        dtD[(row0 + r) * 128 + d] = sp;
    }
    for (int i = tid; i < 256; i += 256) {
        int r = i >> 4, s = i & 15;
        BmD[(row0 + r) * 16 + s] = dbl[r * 36 + 4 + s];
        CmD[(row0 + r) * 16 + s] = dbl[r * 36 + 20 + s];
    }
}

// K6: scan phase A — per-chunk (P = prod dA, S = local scan w/ h0=0)
// 512 threads: d = tid>>2, sq = tid&3 (4 states each). 2-deep prefetch pipeline.
__global__ __launch_bounds__(512) void k_scanA(const float* __restrict__ dt,
        const float* __restrict__ xc, const float* __restrict__ Bm,
        const float* __restrict__ Alog_f, const float* __restrict__ Alog_b,
        float* __restrict__ csP, float* __restrict__ csS) {
    int tid = threadIdx.x;
    int d = tid >> 2, sq = tid & 3;
    int chunk = blockIdx.x;
    int bd = blockIdx.y;                 // dir*2+b
    const float* Alog = (bd >> 1) ? Alog_b : Alog_f;
    float ac[4], h[4], P[4];
#pragma unroll
    for (int s = 0; s < 4; s++) {
        ac[s] = -__expf(Alog[d * 16 + sq * 4 + s]);
        h[s] = 0.f; P[s] = 1.f;
    }
    long base = (long)bd * LL;
    int l0 = chunk * CLEN;
    const float* dtp = dt + (base + l0) * 128 + d;
    const float* xcp = xc + (base + l0) * 128 + d;
    const float4* bm4 = (const float4*)(Bm + (base + l0) * 16) + sq;
    // pipeline: hold l, l+1 in regs; load l+2, l+3 during compute
    float dA0 = dtp[0],   xA0 = xcp[0];   float4 bA0 = bm4[0];
    float dA1 = dtp[128], xA1 = xcp[128]; float4 bA1 = bm4[4];
    for (int l = 0; l < CLEN; l += 2) {
        int l2 = (l + 2 < CLEN) ? (l + 2) : (CLEN - 2);
        float  dB0 = dtp[(long)l2 * 128],       xB0 = xcp[(long)l2 * 128];
        float4 bB0 = bm4[(long)l2 * 4];
        float  dB1 = dtp[(long)(l2 + 1) * 128], xB1 = xcp[(long)(l2 + 1) * 128];
        float4 bB1 = bm4[(long)(l2 + 1) * 4];
        {
            float dtx = dA0 * xA0;
            float bb[4] = {bA0.x, bA0.y, bA0.z, bA0.w};
#pragma unroll
            for (int s = 0; s < 4; s++) {
                float a = __expf(dA0 * ac[s]);
                h[s] = a * h[s] + dtx * bb[s];
                P[s] *= a;
            }
        }
        {
            float dtx = dA1 * xA1;
            float bb[4] = {bA1.x, bA1.y, bA1.z, bA1.w};
#pragma unroll
            for (int s = 0; s < 4; s++) {
                float a = __expf(dA1 * ac[s]);
                h[s] = a * h[s] + dtx * bb[s];
                P[s] *= a;
            }
        }
        dA0 = dB0; xA0 = xB0; bA0 = bB0;
        dA1 = dB1; xA1 = xB1; bA1 = bB1;
    }
    long cso = ((long)bd * NCH + chunk) * 2048 + d * 16 + sq * 4;
    *(float4*)(csP + cso) = (float4){P[0], P[1], P[2], P[3]};
    *(float4*)(csS + cso) = (float4){h[0], h[1], h[2], h[3]};
}

// K7: sequential combine over chunks; csS[c] becomes h_in for chunk c
__global__ void k_combine(const float* __restrict__ csP, float* __restrict__ csS) {
    int idx = blockIdx.x * blockDim.x + threadIdx.x;  // 8192
    int bd = idx >> 11;
    int ds = idx & 2047;
    float hin = 0.f;
#pragma unroll 8
    for (int c = 0; c < NCH; c++) {
        long o = ((long)bd * NCH + c) * 2048 + ds;
        float P = csP[o], S = csS[o];
        csS[o] = hin;
        hin = P * hin + S;
    }
}

// K8: scan phase C — replay with h_in, emit y = (scan + D*xc)*silu(z)
// 512 threads: d = tid>>2, sq = tid&3. 2-level shfl reduce. 2-deep prefetch.
__global__ __launch_bounds__(512) void k_scanC(const float* __restrict__ dt,
        const float* __restrict__ xc, const float* __restrict__ Bm,
        const float* __restrict__ Cm, const float* __restrict__ z,
        const float* __restrict__ csS,
        const float* __restrict__ Alog_f, const float* __restrict__ Alog_b,
        const float* __restrict__ D_f, const float* __restrict__ D_b,
        float* __restrict__ yg) {
    int tid = threadIdx.x;
    int d = tid >> 2, sq = tid & 3;
    int chunk = blockIdx.x;
    int bd = blockIdx.y;
    int dir = bd >> 1;
    const float* Alog = dir ? Alog_b : Alog_f;
    float Dv = dir ? D_b[d] : D_f[d];
    float ac[4], h[4];
    long cso = ((long)bd * NCH + chunk) * 2048 + d * 16 + sq * 4;
    {
        float4 h0 = *(const float4*)(csS + cso);
        h[0] = h0.x; h[1] = h0.y; h[2] = h0.z; h[3] = h0.w;
    }
#pragma unroll
    for (int s = 0; s < 4; s++) ac[s] = -__expf(Alog[d * 16 + sq * 4 + s]);
    long base = (long)bd * LL;
    int l0 = chunk * CLEN;
    const float* dtp = dt + (base + l0) * 128 + d;
    const float* xcp = xc + (base + l0) * 128 + d;
    const float* zp  = z  + (base + l0) * 128 + d;
    const float4* bm4 = (const float4*)(Bm + (base + l0) * 16) + sq;
    const float4* cm4 = (const float4*)(Cm + (base + l0) * 16) + sq;
    float* yp = yg + (base + l0) * 128 + d;
    float  dA0 = dtp[0],   xA0 = xcp[0],   zA0 = zp[0];
    float4 bA0 = bm4[0],   cA0 = cm4[0];
    float  dA1 = dtp[128], xA1 = xcp[128], zA1 = zp[128];
    float4 bA1 = bm4[4],   cA1 = cm4[4];
    for (int l = 0; l < CLEN; l += 2) {
        int l2 = (l + 2 < CLEN) ? (l + 2) : (CLEN - 2);
        float  dB0 = dtp[(long)l2 * 128], xB0 = xcp[(long)l2 * 128], zB0 = zp[(long)l2 * 128];
        float4 bB0 = bm4[(long)l2 * 4],   cB0 = cm4[(long)l2 * 4];
        float  dB1 = dtp[(long)(l2 + 1) * 128], xB1 = xcp[(long)(l2 + 1) * 128], zB1 = zp[(long)(l2 + 1) * 128];
        float4 bB1 = bm4[(long)(l2 + 1) * 4],   cB1 = cm4[(long)(l2 + 1) * 4];
#pragma unroll
        for (int half = 0; half < 2; half++) {
            float dc  = half ? dA1 : dA0;
            float xcc = half ? xA1 : xA0;
            float zc  = half ? zA1 : zA0;
            float4 bq = half ? bA1 : bA0;
            float4 cq = half ? cA1 : cA0;
            float dtx = dc * xcc;
            float bb[4] = {bq.x, bq.y, bq.z, bq.w};
            float cc[4] = {cq.x, cq.y, cq.z, cq.w};
            float y = 0.f;
#pragma unroll
            for (int s = 0; s < 4; s++) {
                float a = __expf(dc * ac[s]);
                h[s] = a * h[s] + dtx * bb[s];
                y += h[s] * cc[s];
            }
            y += __shfl_xor(y, 1, 64);
            y += __shfl_xor(y, 2, 64);
            if (sq == 0) {
                y += Dv * xcc;
                y *= zc / (1.f + __expf(-zc));
                yp[(long)(l + half) * 128] = y;
            }
        }
        dA0 = dB0; xA0 = xB0; zA0 = zB0; bA0 = bB0; cA0 = cB0;
        dA1 = dB1; xA1 = xB1; zA1 = zB1; bA1 = bB1; cA1 = cB1;
    }
}

// K9: out-proj (both dirs) + residual + in-register LN2 via bf16 MFMA -> xo
__global__ __launch_bounds__(256) void k_outln_mfma(const float* __restrict__ yg,
        const float* __restrict__ xf, const __bf16* __restrict__ wbo,
        const float* __restrict__ g2, const float* __restrict__ b2,
        float* __restrict__ xo) {
    __shared__ __align__(16) __bf16 As[64 * 136];   // 17408 B
    __shared__ __align__(16) __bf16 Bs[64 * 136];   // 17408 B
    int tid = threadIdx.x;
    long row0 = (long)blockIdx.x * 64;
    int b = (int)(row0 / LL);
    int l0 = (int)(row0 % LL);
    int wv = tid >> 6, lane = tid & 63, lane15 = lane & 15, q4 = lane >> 4;
    f32x4 acc[4];
#pragma unroll
    for (int i = 0; i < 4; i++) acc[i] = (f32x4){0.f, 0.f, 0.f, 0.f};

    for (int dir = 0; dir < 2; dir++) {
        __syncthreads();
        int r = tid >> 2, q = tid & 3;
        int ls = dir ? (LL - 1 - (l0 + r)) : (l0 + r);
        const float* src = yg + ((long)(dir * 2 + b) * LL + ls) * 128 + q * 32;
        unsigned int* adst = (unsigned int*)As;
#pragma unroll
        for (int k = 0; k < 8; k++) {
            float4 t4 = ((const float4*)src)[k];
            union { unsigned int u; __bf16 h[2]; } p0, p1;
            p0.h[0] = (__bf16)t4.x; p0.h[1] = (__bf16)t4.y;
            p1.h[0] = (__bf16)t4.z; p1.h[1] = (__bf16)t4.w;
            adst[r * 68 + q * 16 + k * 2]     = p0.u;
            adst[r * 68 + q * 16 + k * 2 + 1] = p1.u;
        }
        const unsigned int* wsrc = (const unsigned int*)wbo + (long)dir * 64 * 68;
        unsigned int* bdst = (unsigned int*)Bs;
        for (int i = tid; i < 64 * 68; i += 256) bdst[i] = wsrc[i];
        __syncthreads();
        int arow = wv * 16 + lane15;
#pragma unroll
        for (int ks = 0; ks < 4; ks++) {
            bf16x8 af = *(const bf16x8*)&As[arow * 136 + ks * 32 + q4 * 8];
#pragma unroll
            for (int nt = 0; nt < 4; nt++) {
                bf16x8 bfr = *(const bf16x8*)&Bs[(nt * 16 + lane15) * 136 + ks * 32 + q4 * 8];
                acc[nt] = __builtin_amdgcn_mfma_f32_16x16x32_bf16(af, bfr, acc[nt], 0, 0, 0);
            }
        }
    }
    float vals[4][4];
#pragma unroll
    for (int nt = 0; nt < 4; nt++) {
        int c = nt * 16 + lane15;
#pragma unroll
        for (int reg = 0; reg < 4; reg++) {
            long R = row0 + wv * 16 + q4 * 4 + reg;
            vals[nt][reg] = acc[nt][reg] + xf[R * 64 + c];
        }
    }
#pragma unroll
    for (int reg = 0; reg < 4; reg++) {
        float ssum = vals[0][reg] + vals[1][reg] + vals[2][reg] + vals[3][reg];
#pragma unroll
        for (int m = 1; m < 16; m <<= 1) ssum += __shfl_xor(ssum, m, 64);
        float mean = ssum * (1.f / 64.f);
        float vv = 0.f;
#pragma unroll
        for (int nt = 0; nt < 4; nt++) { float dd = vals[nt][reg] - mean; vv += dd * dd; }
#pragma unroll
        for (int m = 1; m < 16; m <<= 1) vv += __shfl_xor(vv, m, 64);
        float rs = rsqrtf(vv * (1.f / 64.f) + EPSF);
        long R = row0 + wv * 16 + q4 * 4 + reg;
#pragma unroll
        for (int nt = 0; nt < 4; nt++) {
            int c = nt * 16 + lane15;
            xo[R * 64 + c] = (vals[nt][reg] - mean) * rs * g2[c] + b2[c];
        }
    }
}

// K10a: pool stage-1 partials over 128-row slices
__global__ __launch_bounds__(256) void k_pool1(const float* __restrict__ xo,
        float* __restrict__ psum, float* __restrict__ pmax) {
    __shared__ float ss[4][64], sx[4][64];
    int b = blockIdx.x, s = blockIdx.y;
    int tid = threadIdx.x;
    int g = tid >> 6, c = tid & 63;
    float sum = 0.f, mx = -INFINITY;
    const float* base = xo + ((long)b * LL + s * 128) * 64 + c;
    for (int r = g; r < 128; r += 4) {
        float v = base[(long)r * 64];
        sum += v; mx = fmaxf(mx, v);
    }
    ss[g][c] = sum; sx[g][c] = mx;
    __syncthreads();
    if (g == 0) {
        float S = ss[0][c] + ss[1][c] + ss[2][c] + ss[3][c];
        float M = fmaxf(fmaxf(sx[0][c], sx[1][c]), fmaxf(sx[2][c], sx[3][c]));
        psum[(b * 80 + s) * 64 + c] = S;
        pmax[(b * 80 + s) * 64 + c] = M;
    }
}

// K11: pool combine + channel attention
__global__ __launch_bounds__(128) void k_att2(const float* __restrict__ psum,
        const float* __restrict__ pmax,
        const float* __restrict__ w1, const float* __restrict__ w2,
        float* __restrict__ att) {
    __shared__ float pav[2][64], pmx[2][64];
    __shared__ float hs[2][2][32];
    int tid = threadIdx.x;
    {
        int bb = tid >> 6, c = tid & 63;
        float S = 0.f, M = -INFINITY;
#pragma unroll 8
        for (int s = 0; s < 80; s++) {
            S += psum[(bb * 80 + s) * 64 + c];
            M = fmaxf(M, pmax[(bb * 80 + s) * 64 + c]);
        }
        pav[bb][c] = S * (1.f / LL);
        pmx[bb][c] = M;
    }
    __syncthreads();
    {
        int which = tid >> 6, rb = tid & 63, bb = rb >> 5, rr = rb & 31;
        const float* v = which ? pmx[bb] : pav[bb];
        float a = 0.f;
        for (int c = 0; c < 64; c++) a += v[c] * w1[rr * 64 + c];
        hs[which][bb][rr] = fmaxf(a, 0.f);
    }
    __syncthreads();
    int bb = tid >> 6, c = tid & 63;
    float sv = 0.f;
#pragma unroll
    for (int rr = 0; rr < 32; rr++) sv += (hs[0][bb][rr] + hs[1][bb][rr]) * w2[c * 32 + rr];
    att[bb * 64 + c] = 1.f / (1.f + __expf(-sv));
}

// K12: out[b,c,t,h,w] = xo[b,l,c] * att[b,c]  — LDS-transposed, coalesced both ways
__global__ __launch_bounds__(256) void k_final2(const float* __restrict__ xo,
        const float* __restrict__ att, float* __restrict__ out) {
    __shared__ float tile[64][65];
    int b = blockIdx.y;
    int l0 = blockIdx.x * 64;
    int tid = threadIdx.x;
    int g = tid >> 6, lane = tid & 63;
    for (int rr = g; rr < 64; rr += 4)
        tile[rr][lane] = xo[((long)b * LL + l0 + rr) * 64 + lane];
    __syncthreads();
    for (int c = g; c < 64; c += 4) {
        float av = att[b * 64 + c];
        out[((long)(b * 64 + c)) * LL + l0 + lane] = tile[lane][c] * av;
    }
}

extern "C" void kernel_launch(void* const* d_in, const int* in_sizes, int n_in,
                              void* d_out, int out_size, void* d_ws, size_t ws_size,
                              hipStream_t stream) {
    const float* x     = (const float*)d_in[0];
    const float* tdc_w = (const float*)d_in[1];
    const float* bn_g  = (const float*)d_in[2];
    const float* bn_b  = (const float*)d_in[3];
    const float* bn_m  = (const float*)d_in[4];
    const float* bn_v  = (const float*)d_in[5];
    const float* ln1_g = (const float*)d_in[6];
    const float* ln1_b = (const float*)d_in[7];
    const float* ln2_g = (const float*)d_in[8];
    const float* ln2_b = (const float*)d_in[9];
    const float* ca_w1 = (const float*)d_in[10];
    const float* ca_w2 = (const float*)d_in[11];
    const float* f_in_w    = (const float*)d_in[12];
    const float* f_conv_w  = (const float*)d_in[13];
    const float* f_conv_b  = (const float*)d_in[14];
    const float* f_xproj_w = (const float*)d_in[15];
    const float* f_dt_w    = (const float*)d_in[16];
    const float* f_dt_b    = (const float*)d_in[17];
    const float* f_A_log   = (const float*)d_in[18];
    const float* f_D       = (const float*)d_in[19];
    const float* f_out_w   = (const float*)d_in[20];
    const float* b_in_w    = (const float*)d_in[21];
    const float* b_conv_w  = (const float*)d_in[22];
    const float* b_conv_b  = (const float*)d_in[23];
    const float* b_xproj_w = (const float*)d_in[24];
    const float* b_dt_w    = (const float*)d_in[25];
    const float* b_dt_b    = (const float*)d_in[26];
    const float* b_A_log   = (const float*)d_in[27];
    const float* b_D       = (const float*)d_in[28];
    const float* b_out_w   = (const float*)d_in[29];

    float* ws = (float*)d_ws;
    __bf16* wbf = (__bf16*)(ws + OFF_WEFF);
    float* xf   = ws + OFF_XF;
    __bf16* wbx = (__bf16*)(ws + OFF_WBX);
    __bf16* wbo = (__bf16*)(ws + OFF_WBO);
    float* psum = ws + OFF_PSUM;
    float* pmax = ws + OFF_PMAX;
    float* xin  = ws + OFF_XIN;   // reused as yg after k_conv1d consumes it
    float* z    = ws + OFF_Z;
    float* xc   = ws + OFF_XC;
    float* dt   = ws + OFF_DT;
    float* Bm   = ws + OFF_BM;
    float* Cm   = ws + OFF_CM;
    float* csP  = ws + OFF_CSP;
    float* csS  = ws + OFF_CSS;
    float* xo   = ws + OFF_XO;
    float* att  = ws + OFF_ATT;
    float* yg   = xin;

    hipLaunchKernelGGL(k_fold, dim3(16), dim3(256), 0, stream, tdc_w, wbf);
    hipLaunchKernelGGL(k_prep, dim3(144), dim3(256), 0, stream,
                       f_in_w, b_in_w, f_out_w, b_out_w, wbx, wbo);
    hipLaunchKernelGGL(k_conv3d_mfma, dim3(2 * TT * 2), dim3(256), 0, stream,
                       x, wbf, bn_g, bn_b, bn_m, bn_v, xf);
    hipLaunchKernelGGL(k_xz_mfma, dim3(2 * LL / 64, 2), dim3(256), 0, stream,
                       xf, wbx, ln1_g, ln1_b, xin, z);
    hipLaunchKernelGGL(k_conv1d, dim3((2 * 2 * LL * DI) / 256), dim3(256), 0, stream,
                       xin, f_conv_w, f_conv_b, b_conv_w, b_conv_b, xc);
    hipLaunchKernelGGL(k_xproj, dim3(2 * LL / 16, 2), dim3(256), 0, stream,
                       xc, f_xproj_w, b_xproj_w, f_dt_w, f_dt_b, b_dt_w, b_dt_b,
                       dt, Bm, Cm);
    hipLaunchKernelGGL(k_scanA, dim3(NCH, 4), dim3(512), 0, stream,
                       dt, xc, Bm, f_A_log, b_A_log, csP, csS);
    hipLaunchKernelGGL(k_combine, dim3(32), dim3(256), 0, stream, csP, csS);
    hipLaunchKernelGGL(k_scanC, dim3(NCH, 4), dim3(512), 0, stream,
                       dt, xc, Bm, Cm, z, csS, f_A_log, b_A_log, f_D, b_D, yg);
    hipLaunchKernelGGL(k_outln_mfma, dim3(2 * LL / 64), dim3(256), 0, stream,
                       yg, xf, wbo, ln2_g, ln2_b, xo);
    hipLaunchKernelGGL(k_pool1, dim3(2, 80), dim3(256), 0, stream, xo, psum, pmax);
    hipLaunchKernelGGL(k_att2, dim3(1), dim3(128), 0, stream, psum, pmax, ca_w1, ca_w2, att);
    hipLaunchKernelGGL(k_final2, dim3(160, 2), dim3(256), 0, stream,
                       xo, att, (float*)d_out);
}